// Round 10
// baseline (149.375 us; speedup 1.0000x reference)
//
#include <hip/hip_runtime.h>
#include <hip/hip_bf16.h>
#include <math.h>

#define Nn    512
#define CS    384
#define CZ    128
#define CH    16
#define Hh    12
#define PQ    4
#define PV    8
#define NCOL  1152   // 192*3 + 144*2 + 288
#define FIN   2112

#define W_C   0.23570226039551584f   // sqrt(2/(9*4))
#define W_L   0.5773502691896258f    // sqrt(1/3)

typedef unsigned short ushort_t;
typedef __attribute__((ext_vector_type(8))) short bf16x8;
typedef __attribute__((ext_vector_type(4))) float f32x4;

// ---------------- workspace layout (float offsets) ----------------
#define OFF_P      0u
#define OFF_MQ     589824u
#define OFF_MK     595968u
#define OFF_VT     602112u      // v16T  [192][512] bf16
#define OFF_VPT    651264u      // vpgT  [288][512] bf16
#define OFF_S16    1830912u     // s bf16 [512][384]      = 98304 floats
#define OFF_WCT    1929216u     // WcatT bf16 [1152][384] = 221184 floats
#define OFF_WFT    2150400u     // WfT bf16 [384][2112]   = 405504 floats
#define OFF_F16    2555904u     // feat bf16 [512][2112]  = 540672 floats (ends 3096576)
#define OFF_PP     3145728u     // partials [512][2][2048] f32 = 2097152 floats (ends 5242880)
#define OFF_EKB    21755904u
#define OFF_EQB    21854208u
#define OFF_WBF    21952512u

__device__ inline ushort_t f2bf(float f) {
  __hip_bfloat16 h = __float2bfloat16(f);
  return *reinterpret_cast<ushort_t*>(&h);
}
__device__ inline float bf2f(ushort_t u) {
  unsigned int x = ((unsigned int)u) << 16;
  return __uint_as_float(x);
}

// ============ K0a: s_i -> bf16 ==============================================
__global__ __launch_bounds__(256) void k_s16(
    const float* __restrict__ s, ushort_t* __restrict__ s16) {
  int idx = blockIdx.x * 256 + threadIdx.x;        // < 196608
  s16[idx] = f2bf(s[idx]);
}

// ============ K0b: WcatT[col][k] bf16 from 6 weight arrays ==================
__global__ __launch_bounds__(384) void k_wcatT(
    const float* __restrict__ Wq, const float* __restrict__ Wk,
    const float* __restrict__ Wv, const float* __restrict__ Wqp,
    const float* __restrict__ Wkp, const float* __restrict__ Wvp,
    ushort_t* __restrict__ WcatT) {
  int col = blockIdx.x;                            // 0..1151
  int k = threadIdx.x;                             // 0..383
  float v;
  if      (col < 192)  v = Wq [k * 192 + col];
  else if (col < 384)  v = Wk [k * 192 + col - 192];
  else if (col < 576)  v = Wv [k * 192 + col - 384];
  else if (col < 720)  v = Wqp[k * 144 + col - 576];
  else if (col < 864)  v = Wkp[k * 144 + col - 720];
  else                 v = Wvp[k * 288 + col - 864];
  WcatT[(size_t)col * CS + k] = f2bf(v);
}

// ============ K0c: WfT[o][f] bf16 from Wf[f][o] =============================
__global__ __launch_bounds__(256) void k_wfT(
    const float* __restrict__ Wf, ushort_t* __restrict__ WfT) {
  int o = blockIdx.x;                              // 0..383
  for (int f = threadIdx.x; f < FIN; f += 256)
    WfT[(size_t)o * FIN + f] = f2bf(Wf[(size_t)f * CS + o]);
}

// ============ K1: proj via MFMA: P = s16 @ WcatT^T (f32 out) ================
__global__ __launch_bounds__(64) void k_projm(
    const ushort_t* __restrict__ s16, const ushort_t* __restrict__ WcatT,
    float* __restrict__ P) {
  int colt = blockIdx.x;                           // 0..71
  int i0 = blockIdx.y * 16;                        // 0..496
  int l = threadIdx.x;
  int cl = l & 15, lk = l >> 4;
  f32x4 acc = {0.f, 0.f, 0.f, 0.f};
  const ushort_t* arow = s16 + (size_t)(i0 + cl) * CS;
  const ushort_t* brow = WcatT + (size_t)(colt * 16 + cl) * CS;
#pragma unroll
  for (int kk = 0; kk < 12; ++kk) {
    bf16x8 a = *(const bf16x8*)(arow + kk * 32 + lk * 8);
    bf16x8 b = *(const bf16x8*)(brow + kk * 32 + lk * 8);
    acc = __builtin_amdgcn_mfma_f32_16x16x32_bf16(a, b, acc, 0, 0, 0);
  }
#pragma unroll
  for (int r = 0; r < 4; ++r)
    P[(size_t)(i0 + lk * 4 + r) * NCOL + colt * 16 + cl] = acc[r];
}

// ===== K1b: rigid transforms -> eqb/ekb bf16, mq/mk, v16T, vpgT =============
__global__ __launch_bounds__(64) void k_prep(
    const float* __restrict__ P, const float* __restrict__ rot,
    const float* __restrict__ trans, const float* __restrict__ gamma,
    ushort_t* __restrict__ eqb, ushort_t* __restrict__ ekb,
    float* __restrict__ mq, float* __restrict__ mk,
    ushort_t* __restrict__ vT, ushort_t* __restrict__ vpT) {
  int gid = blockIdx.x * 64 + threadIdx.x;        // < 6144
  int i = gid / Hh, h = gid % Hh;
  const float* Pi = P + (size_t)i * NCOL;
  float R[9], T[3];
#pragma unroll
  for (int m = 0; m < 9; ++m) R[m] = rot[i * 9 + m];
#pragma unroll
  for (int m = 0; m < 3; ++m) T[m] = trans[i * 3 + m];
  float cg = W_C * gamma[h];

  ushort_t* eq = eqb + (size_t)gid * 32;
  ushort_t* ek = ekb + (size_t)gid * 32;
#pragma unroll
  for (int d = 0; d < CH; ++d) eq[d] = f2bf(Pi[h * CH + d] * 0.25f);   // q/sqrt(16)
#pragma unroll
  for (int d = 0; d < CH; ++d) ek[d] = f2bf(Pi[192 + h * CH + d]);     // k
  float sq = 0.f, sk = 0.f;
#pragma unroll
  for (int p = 0; p < PQ; ++p) {
    float x = Pi[576 + h * 12 + p * 3 + 0];
    float y = Pi[576 + h * 12 + p * 3 + 1];
    float zc = Pi[576 + h * 12 + p * 3 + 2];
    float gx = R[0] * x + R[1] * y + R[2] * zc + T[0];
    float gy = R[3] * x + R[4] * y + R[5] * zc + T[1];
    float gz = R[6] * x + R[7] * y + R[8] * zc + T[2];
    eq[16 + p * 3 + 0] = f2bf(cg * gx);
    eq[16 + p * 3 + 1] = f2bf(cg * gy);
    eq[16 + p * 3 + 2] = f2bf(cg * gz);
    sq += gx * gx + gy * gy + gz * gz;
  }
#pragma unroll
  for (int p = 0; p < PQ; ++p) {
    float x = Pi[720 + h * 12 + p * 3 + 0];
    float y = Pi[720 + h * 12 + p * 3 + 1];
    float zc = Pi[720 + h * 12 + p * 3 + 2];
    float gx = R[0] * x + R[1] * y + R[2] * zc + T[0];
    float gy = R[3] * x + R[4] * y + R[5] * zc + T[1];
    float gz = R[6] * x + R[7] * y + R[8] * zc + T[2];
    ek[16 + p * 3 + 0] = f2bf(gx);
    ek[16 + p * 3 + 1] = f2bf(gy);
    ek[16 + p * 3 + 2] = f2bf(gz);
    sk += gx * gx + gy * gy + gz * gz;
  }
#pragma unroll
  for (int d = 28; d < 32; ++d) { eq[d] = 0; ek[d] = 0; }
  mq[gid] = -0.5f * cg * sq;
  mk[gid] = -0.5f * cg * sk;

#pragma unroll
  for (int d = 0; d < CH; ++d)
    vT[(size_t)(h * CH + d) * Nn + i] = f2bf(Pi[384 + h * CH + d]);
#pragma unroll
  for (int p = 0; p < PV; ++p) {
    float x = Pi[864 + h * 24 + p * 3 + 0];
    float y = Pi[864 + h * 24 + p * 3 + 1];
    float zc = Pi[864 + h * 24 + p * 3 + 2];
    vpT[(size_t)(h * 24 + p * 3 + 0) * Nn + i] = f2bf(R[0] * x + R[1] * y + R[2] * zc + T[0]);
    vpT[(size_t)(h * 24 + p * 3 + 1) * Nn + i] = f2bf(R[3] * x + R[4] * y + R[5] * zc + T[1]);
    vpT[(size_t)(h * 24 + p * 3 + 2) * Nn + i] = f2bf(R[6] * x + R[7] * y + R[8] * zc + T[2]);
  }
}

// ===== K1c: Wb B-fragments (dense): wbf[kk][lane][e] for 16x16x32 MFMA ======
__global__ __launch_bounds__(256) void k_wbfrag(
    const float* __restrict__ Wb, ushort_t* __restrict__ wbf) {
  int t = threadIdx.x;            // 256 = 4 ksteps * 64 lanes
  int kk = t >> 6, l = t & 63;
  int h = l & 15, lk = l >> 4;
#pragma unroll
  for (int e = 0; e < 8; ++e) {
    int c = kk * 32 + lk * 8 + e;
    wbf[t * 8 + e] = (h < Hh) ? f2bf(Wb[c * Hh + h]) : (ushort_t)0;
  }
}

// ======== K2: fused flash, block per (i, j-half), 8 waves ====================
// Wave w owns 32 j's of its half. Partial output (unnormalized) + (M,L) -> pp.
__global__ __launch_bounds__(512, 8) void k_fused4(
    const float* __restrict__ z, const ushort_t* __restrict__ eqb,
    const ushort_t* __restrict__ ekb, const ushort_t* __restrict__ wbf,
    const float* __restrict__ mk,
    const ushort_t* __restrict__ vT, const ushort_t* __restrict__ vpT,
    float* __restrict__ pp) {
  __shared__ float smemf[2336];                    // 9344 B
  char*  pB = (char*)smemf;                        // P: [16][256] u16, swizzled (8KB)
  float* mb = smemf + 2048;                        // [8][16]
  float* lb = smemf + 2176;                        // [8][16]
  float* Mv = smemf + 2304;                        // [16]

  int i = blockIdx.x, half = blockIdx.y, tid = threadIdx.x;
  int l = tid & 63, w = tid >> 6;                  // 8 waves
  int cl = l & 15, lk = l >> 4;
  int j0b = half * 256;
  float* po = pp + ((size_t)i * 2 + half) * 2048;
  const float* zb = z + (size_t)i * Nn * CZ;
  int swz = (cl & 7) << 4;

  bf16x8 zer;
#pragma unroll
  for (int e = 0; e < 8; ++e) zer[e] = 0;

  bf16x8 wbreg[4];
#pragma unroll
  for (int kk = 0; kk < 4; ++kk)
    wbreg[kk] = *(const bf16x8*)&wbf[(kk * 64 + l) * 8];
  bf16x8 eqsel = zer;
  if (cl < Hh) eqsel = *(const bf16x8*)&eqb[((size_t)i * Hh + cl) * 32 + lk * 8];

  // ---- Phase 1: logits for wave's 32 j (2 groups of 16) ----
  float v[2][4];
#pragma unroll
  for (int cg = 0; cg < 2; ++cg) {
    int jt = w * 32 + cg * 16;                     // local j base
    int jrow = j0b + jt + cl;                      // global j (A row)
    f32x4 dl = {0.f, 0.f, 0.f, 0.f};
#pragma unroll
    for (int kk = 0; kk < 4; ++kk) {
      const float4* zp = (const float4*)(zb + (size_t)jrow * CZ + (kk * 4 + lk) * 8);
      float4 x0 = zp[0], x1 = zp[1];
      bf16x8 a;
      a[0] = (short)f2bf(x0.x); a[1] = (short)f2bf(x0.y);
      a[2] = (short)f2bf(x0.z); a[3] = (short)f2bf(x0.w);
      a[4] = (short)f2bf(x1.x); a[5] = (short)f2bf(x1.y);
      a[6] = (short)f2bf(x1.z); a[7] = (short)f2bf(x1.w);
      dl = __builtin_amdgcn_mfma_f32_16x16x32_bf16(a, wbreg[kk], dl, 0, 0, 0);
    }
#pragma unroll
    for (int hp = 0; hp < Hh; ++hp) {
      bf16x8 a = *(const bf16x8*)&ekb[((size_t)jrow * Hh + hp) * 32 + lk * 8];
      bf16x8 b = (cl == hp) ? eqsel : zer;
      dl = __builtin_amdgcn_mfma_f32_16x16x32_bf16(a, b, dl, 0, 0, 0);
    }
    int jb = j0b + jt + lk * 4;                    // global j of D rows
    if (cl < Hh) {
#pragma unroll
      for (int r = 0; r < 4; ++r) v[cg][r] = W_L * (dl[r] + mk[(jb + r) * Hh + cl]);
    } else {
#pragma unroll
      for (int r = 0; r < 4; ++r) v[cg][r] = -1e30f;
    }
  }

  // ---- Phase 2: per-wave softmax over 32 j (head = cl) ----
  float m_w = v[0][0];
#pragma unroll
  for (int cg = 0; cg < 2; ++cg)
#pragma unroll
    for (int r = 0; r < 4; ++r) m_w = fmaxf(m_w, v[cg][r]);
  m_w = fmaxf(m_w, __shfl_xor(m_w, 16));
  m_w = fmaxf(m_w, __shfl_xor(m_w, 32));

  float ps = 0.f;
#pragma unroll
  for (int cg = 0; cg < 2; ++cg) {
    int j = w * 32 + cg * 16 + lk * 4;             // local j
    ushort_t p0 = f2bf(__expf(v[cg][0] - m_w));
    ushort_t p1 = f2bf(__expf(v[cg][1] - m_w));
    ushort_t p2 = f2bf(__expf(v[cg][2] - m_w));
    ushort_t p3 = f2bf(__expf(v[cg][3] - m_w));
    ps += bf2f(p0) + bf2f(p1) + bf2f(p2) + bf2f(p3);
    uint2 d;
    d.x = (unsigned int)p0 | ((unsigned int)p1 << 16);
    d.y = (unsigned int)p2 | ((unsigned int)p3 << 16);
    *(uint2*)&pB[(cl * 512 + j * 2) ^ swz] = d;
  }
  ps += __shfl_xor(ps, 16);
  ps += __shfl_xor(ps, 32);
  if (lk == 0) { mb[w * 16 + cl] = m_w; lb[w * 16 + cl] = ps; }
  __syncthreads();                                 // #1

  if (tid < 16) {
    float M = mb[tid];
#pragma unroll
    for (int ww = 1; ww < 8; ++ww) M = fmaxf(M, mb[ww * 16 + tid]);
    float L = 0.f;
#pragma unroll
    for (int ww = 0; ww < 8; ++ww) L += lb[ww * 16 + tid] * __expf(mb[ww * 16 + tid] - M);
    Mv[tid] = M;
    po[2016 + tid] = M;                            // per-head block max
    po[2032 + tid] = L;                            // per-head block sum
  }
  __syncthreads();                                 // #2

  // ---- Phase 3: rescale own P slice by exp(m_w - M_block) ----
  float sf = __expf(m_w - Mv[cl]);
#pragma unroll
  for (int q = 0; q < 2; ++q) {
    int j = w * 32 + lk * 8 + q * 4;               // local j
    unsigned int off = (unsigned int)(cl * 512 + j * 2) ^ swz;
    uint2 d = *(uint2*)&pB[off];
    ushort_t q0 = f2bf(bf2f((ushort_t)(d.x & 0xffff)) * sf);
    ushort_t q1 = f2bf(bf2f((ushort_t)(d.x >> 16)) * sf);
    ushort_t q2 = f2bf(bf2f((ushort_t)(d.y & 0xffff)) * sf);
    ushort_t q3 = f2bf(bf2f((ushort_t)(d.y >> 16)) * sf);
    d.x = (unsigned int)q0 | ((unsigned int)q1 << 16);
    d.y = (unsigned int)q2 | ((unsigned int)q3 << 16);
    *(uint2*)&pB[off] = d;
  }
  __syncthreads();                                 // #3

  // ---- Phase 4: attend over this half's 256 j, wave owns t = w + 8n ----
  f32x4 acc[5];
#pragma unroll
  for (int n = 0; n < 5; ++n) acc[n] = (f32x4){0.f, 0.f, 0.f, 0.f};

  for (int kk = 0; kk < 8; ++kk) {
    int koff = kk * 32 + lk * 8;                   // local j
    int jg = j0b + koff;                           // global j
    bf16x8 af = *(const bf16x8*)&pB[(cl * 512 + koff * 2) ^ swz];
#pragma unroll
    for (int n = 0; n < 5; ++n) {
      int t = w + n * 8;
      if (t < 38) {
        bf16x8 bfr;
        if (t < 8) {                               // o_pair: z^T from global/L2
          const float* zc = zb + (size_t)jg * CZ + t * 16 + cl;
#pragma unroll
          for (int e = 0; e < 8; ++e) bfr[e] = (short)f2bf(zc[e * CZ]);
        } else if (t < 20) {
          bfr = *(const bf16x8*)(vT + (size_t)((t - 8) * 16 + cl) * Nn + jg);
        } else {
          bfr = *(const bf16x8*)(vpT + (size_t)((t - 20) * 16 + cl) * Nn + jg);
        }
        acc[n] = __builtin_amdgcn_mfma_f32_16x16x32_bf16(af, bfr, acc[n], 0, 0, 0);
      }
    }
  }

  // ---- store raw partial acc (no normalization) ----
#pragma unroll
  for (int n = 0; n < 5; ++n) {
    int t = w + n * 8;
    if (t < 38) {
      if (t < 8) {
        int c = t * 16 + cl;
#pragma unroll
        for (int r = 0; r < 4; ++r) {
          int h = lk * 4 + r;
          if (h < Hh) po[h * CZ + c] = acc[n][r];
        }
      } else if (t < 20) {
        int h = t - 8;
        if (lk == (h >> 2)) po[1536 + h * CH + cl] = acc[n][h & 3];
      } else {
        int cp = (t - 20) * 16 + cl;
        int h = cp / 24;
        if (lk == (h >> 2)) po[1728 + cp] = acc[n][h & 3];
      }
    }
  }
}

// ======== K3: merge halves + normalize + invert-apply + norm -> feat16 ======
__global__ __launch_bounds__(256) void k_merge(
    const float* __restrict__ pp, const float* __restrict__ rot,
    const float* __restrict__ trans, ushort_t* __restrict__ feat16) {
  __shared__ float a0s[16], a1s[16];
  __shared__ float optg[288];
  int i = blockIdx.x, tid = threadIdx.x;
  const float* p0 = pp + ((size_t)i * 2 + 0) * 2048;
  const float* p1 = pp + ((size_t)i * 2 + 1) * 2048;
  ushort_t* Fi = feat16 + (size_t)i * FIN;

  if (tid < 16) {
    float m0 = p0[2016 + tid], m1 = p1[2016 + tid];
    float M = fmaxf(m0, m1);
    float s0 = __expf(m0 - M), s1 = __expf(m1 - M);
    float L = p0[2032 + tid] * s0 + p1[2032 + tid] * s1;
    float inv = (tid < Hh) ? 1.f / L : 0.f;
    a0s[tid] = s0 * inv;
    a1s[tid] = s1 * inv;
  }
  __syncthreads();

  for (int idx = tid; idx < 1728; idx += 256) {
    int h = (idx < 1536) ? (idx >> 7) : ((idx - 1536) >> 4);
    Fi[idx] = f2bf(p0[idx] * a0s[h] + p1[idx] * a1s[h]);
  }
  for (int idx = tid; idx < 288; idx += 256) {
    int h = idx / 24;
    optg[idx] = p0[1728 + idx] * a0s[h] + p1[1728 + idx] * a1s[h];
  }
  __syncthreads();

  if (tid < 96) {
    int h = tid >> 3, p = tid & 7;
    int cp = h * 24 + p * 3;
    float g0 = optg[cp + 0] - trans[i * 3 + 0];
    float g1 = optg[cp + 1] - trans[i * 3 + 1];
    float g2 = optg[cp + 2] - trans[i * 3 + 2];
    const float* R = rot + i * 9;
    float ss = 0.f;
#pragma unroll
    for (int nn2 = 0; nn2 < 3; ++nn2) {
      float o = R[nn2] * g0 + R[3 + nn2] * g1 + R[6 + nn2] * g2;   // R^T (g - t)
      Fi[1728 + cp + nn2] = f2bf(o);
      ss += o * o;
    }
    Fi[2016 + h * 8 + p] = f2bf(sqrtf(ss + 1e-12f));
  }
}

// ============ K5: out = feat16 @ WfT^T + bf (MFMA) ==========================
__global__ __launch_bounds__(64) void k_outm(
    const ushort_t* __restrict__ feat16, const ushort_t* __restrict__ WfT,
    const float* __restrict__ bfv, float* __restrict__ out) {
  int ot = blockIdx.x;                             // 0..23
  int i0 = blockIdx.y * 16;
  int l = threadIdx.x;
  int cl = l & 15, lk = l >> 4;
  f32x4 acc = {0.f, 0.f, 0.f, 0.f};
  const ushort_t* arow = feat16 + (size_t)(i0 + cl) * FIN;
  const ushort_t* brow = WfT + (size_t)(ot * 16 + cl) * FIN;
#pragma unroll 6
  for (int kk = 0; kk < 66; ++kk) {
    bf16x8 a = *(const bf16x8*)(arow + kk * 32 + lk * 8);
    bf16x8 b = *(const bf16x8*)(brow + kk * 32 + lk * 8);
    acc = __builtin_amdgcn_mfma_f32_16x16x32_bf16(a, b, acc, 0, 0, 0);
  }
  float bias = bfv[ot * 16 + cl];
#pragma unroll
  for (int r = 0; r < 4; ++r)
    out[(size_t)(i0 + lk * 4 + r) * CS + ot * 16 + cl] = acc[r] + bias;
}

// ============================ launcher ======================================
extern "C" void kernel_launch(void* const* d_in, const int* in_sizes, int n_in,
                              void* d_out, int out_size, void* d_ws, size_t ws_size,
                              hipStream_t stream) {
  const float* s_i   = (const float*)d_in[0];
  const float* z_ij  = (const float*)d_in[1];
  const float* rot   = (const float*)d_in[2];
  const float* trans = (const float*)d_in[3];
  const float* Wq    = (const float*)d_in[4];
  const float* Wk    = (const float*)d_in[5];
  const float* Wv    = (const float*)d_in[6];
  const float* Wqp   = (const float*)d_in[7];
  const float* Wkp   = (const float*)d_in[8];
  const float* Wvp   = (const float*)d_in[9];
  const float* Wb    = (const float*)d_in[10];
  const float* gamma = (const float*)d_in[11];
  const float* Wf    = (const float*)d_in[12];
  const float* bf    = (const float*)d_in[13];
  float* out = (float*)d_out;

  float* w = (float*)d_ws;
  float*    P    = w + OFF_P;
  float*    mq   = w + OFF_MQ;
  float*    mk   = w + OFF_MK;
  ushort_t* vT   = (ushort_t*)(w + OFF_VT);
  ushort_t* vpT  = (ushort_t*)(w + OFF_VPT);
  ushort_t* s16  = (ushort_t*)(w + OFF_S16);
  ushort_t* WcT  = (ushort_t*)(w + OFF_WCT);
  ushort_t* WfT  = (ushort_t*)(w + OFF_WFT);
  ushort_t* f16  = (ushort_t*)(w + OFF_F16);
  float*    pp   = w + OFF_PP;
  ushort_t* ekb  = (ushort_t*)(w + OFF_EKB);
  ushort_t* eqb  = (ushort_t*)(w + OFF_EQB);
  ushort_t* wbf  = (ushort_t*)(w + OFF_WBF);

  k_s16<<<768, 256, 0, stream>>>(s_i, s16);
  k_wcatT<<<1152, 384, 0, stream>>>(Wq, Wk, Wv, Wqp, Wkp, Wvp, WcT);
  k_wfT<<<384, 256, 0, stream>>>(Wf, WfT);
  k_projm<<<dim3(72, 32), 64, 0, stream>>>(s16, WcT, P);
  k_prep<<<96, 64, 0, stream>>>(P, rot, trans, gamma, eqb, ekb, mq, mk, vT, vpT);
  k_wbfrag<<<1, 256, 0, stream>>>(Wb, wbf);
  k_fused4<<<dim3(512, 2), 512, 0, stream>>>(z_ij, eqb, ekb, wbf, mk, vT, vpT, pp);
  k_merge<<<512, 256, 0, stream>>>(pp, rot, trans, f16);
  k_outm<<<dim3(24, 32), 64, 0, stream>>>(f16, WfT, bf, out);
}

// Round 11
// 130.271 us; speedup vs baseline: 1.1466x; 1.1466x over previous
//
#include <hip/hip_runtime.h>
#include <hip/hip_bf16.h>
#include <math.h>

#define Nn    512
#define CS    384
#define CZ    128
#define CH    16
#define Hh    12
#define PQ    4
#define PV    8
#define NCOL  1152   // 192*3 + 144*2 + 288
#define FIN   2112

#define W_C   0.23570226039551584f   // sqrt(2/(9*4))
#define W_L   0.5773502691896258f    // sqrt(1/3)

typedef unsigned short ushort_t;
typedef __attribute__((ext_vector_type(8))) short bf16x8;
typedef __attribute__((ext_vector_type(4))) float f32x4;

// ---------------- workspace layout (float offsets) ----------------
#define OFF_P      0u
#define OFF_MQ     589824u
#define OFF_MK     595968u
#define OFF_VT     602112u      // v16T  [192][512] bf16
#define OFF_VPT    651264u      // vpgT  [288][512] bf16
#define OFF_S16    1830912u     // s bf16 [512][384]      = 98304 floats
#define OFF_WCT    1929216u     // WcatT bf16 [1152][384] = 221184 floats
#define OFF_WFT    2150400u     // WfT bf16 [384][2112]   = 405504 floats
#define OFF_F16    2555904u     // feat bf16 [512][2112]  = 540672 floats (ends 3096576)
#define OFF_PP     3145728u     // partials [512][2][2048] f32 = 2097152 floats (ends 5242880)
#define OFF_EKB    21755904u
#define OFF_EQB    21854208u
#define OFF_WBF    21952512u

__device__ inline ushort_t f2bf(float f) {
  __hip_bfloat16 h = __float2bfloat16(f);
  return *reinterpret_cast<ushort_t*>(&h);
}
__device__ inline float bf2f(ushort_t u) {
  unsigned int x = ((unsigned int)u) << 16;
  return __uint_as_float(x);
}

// ============ K0a: s_i -> bf16 ==============================================
__global__ __launch_bounds__(256) void k_s16(
    const float* __restrict__ s, ushort_t* __restrict__ s16) {
  int idx = blockIdx.x * 256 + threadIdx.x;        // < 196608
  s16[idx] = f2bf(s[idx]);
}

// ============ K0b: WcatT[col][k] bf16 from 6 weight arrays ==================
__global__ __launch_bounds__(384) void k_wcatT(
    const float* __restrict__ Wq, const float* __restrict__ Wk,
    const float* __restrict__ Wv, const float* __restrict__ Wqp,
    const float* __restrict__ Wkp, const float* __restrict__ Wvp,
    ushort_t* __restrict__ WcatT) {
  int col = blockIdx.x;                            // 0..1151
  int k = threadIdx.x;                             // 0..383
  float v;
  if      (col < 192)  v = Wq [k * 192 + col];
  else if (col < 384)  v = Wk [k * 192 + col - 192];
  else if (col < 576)  v = Wv [k * 192 + col - 384];
  else if (col < 720)  v = Wqp[k * 144 + col - 576];
  else if (col < 864)  v = Wkp[k * 144 + col - 720];
  else                 v = Wvp[k * 288 + col - 864];
  WcatT[(size_t)col * CS + k] = f2bf(v);
}

// ============ K0c: WfT[o][f] bf16 from Wf[f][o] =============================
__global__ __launch_bounds__(256) void k_wfT(
    const float* __restrict__ Wf, ushort_t* __restrict__ WfT) {
  int o = blockIdx.x;                              // 0..383
  for (int f = threadIdx.x; f < FIN; f += 256)
    WfT[(size_t)o * FIN + f] = f2bf(Wf[(size_t)f * CS + o]);
}

// ============ K1: proj via MFMA: P = s16 @ WcatT^T (f32 out) ================
__global__ __launch_bounds__(64) void k_projm(
    const ushort_t* __restrict__ s16, const ushort_t* __restrict__ WcatT,
    float* __restrict__ P) {
  int colt = blockIdx.x;                           // 0..71
  int i0 = blockIdx.y * 16;                        // 0..496
  int l = threadIdx.x;
  int cl = l & 15, lk = l >> 4;
  f32x4 acc = {0.f, 0.f, 0.f, 0.f};
  const ushort_t* arow = s16 + (size_t)(i0 + cl) * CS;
  const ushort_t* brow = WcatT + (size_t)(colt * 16 + cl) * CS;
#pragma unroll
  for (int kk = 0; kk < 12; ++kk) {
    bf16x8 a = *(const bf16x8*)(arow + kk * 32 + lk * 8);
    bf16x8 b = *(const bf16x8*)(brow + kk * 32 + lk * 8);
    acc = __builtin_amdgcn_mfma_f32_16x16x32_bf16(a, b, acc, 0, 0, 0);
  }
#pragma unroll
  for (int r = 0; r < 4; ++r)
    P[(size_t)(i0 + lk * 4 + r) * NCOL + colt * 16 + cl] = acc[r];
}

// ===== K1b: rigid transforms -> eqb/ekb bf16, mq/mk, v16T, vpgT =============
__global__ __launch_bounds__(64) void k_prep(
    const float* __restrict__ P, const float* __restrict__ rot,
    const float* __restrict__ trans, const float* __restrict__ gamma,
    ushort_t* __restrict__ eqb, ushort_t* __restrict__ ekb,
    float* __restrict__ mq, float* __restrict__ mk,
    ushort_t* __restrict__ vT, ushort_t* __restrict__ vpT) {
  int gid = blockIdx.x * 64 + threadIdx.x;        // < 6144
  int i = gid / Hh, h = gid % Hh;
  const float* Pi = P + (size_t)i * NCOL;
  float R[9], T[3];
#pragma unroll
  for (int m = 0; m < 9; ++m) R[m] = rot[i * 9 + m];
#pragma unroll
  for (int m = 0; m < 3; ++m) T[m] = trans[i * 3 + m];
  float cg = W_C * gamma[h];

  ushort_t* eq = eqb + (size_t)gid * 32;
  ushort_t* ek = ekb + (size_t)gid * 32;
#pragma unroll
  for (int d = 0; d < CH; ++d) eq[d] = f2bf(Pi[h * CH + d] * 0.25f);   // q/sqrt(16)
#pragma unroll
  for (int d = 0; d < CH; ++d) ek[d] = f2bf(Pi[192 + h * CH + d]);     // k
  float sq = 0.f, sk = 0.f;
#pragma unroll
  for (int p = 0; p < PQ; ++p) {
    float x = Pi[576 + h * 12 + p * 3 + 0];
    float y = Pi[576 + h * 12 + p * 3 + 1];
    float zc = Pi[576 + h * 12 + p * 3 + 2];
    float gx = R[0] * x + R[1] * y + R[2] * zc + T[0];
    float gy = R[3] * x + R[4] * y + R[5] * zc + T[1];
    float gz = R[6] * x + R[7] * y + R[8] * zc + T[2];
    eq[16 + p * 3 + 0] = f2bf(cg * gx);
    eq[16 + p * 3 + 1] = f2bf(cg * gy);
    eq[16 + p * 3 + 2] = f2bf(cg * gz);
    sq += gx * gx + gy * gy + gz * gz;
  }
#pragma unroll
  for (int p = 0; p < PQ; ++p) {
    float x = Pi[720 + h * 12 + p * 3 + 0];
    float y = Pi[720 + h * 12 + p * 3 + 1];
    float zc = Pi[720 + h * 12 + p * 3 + 2];
    float gx = R[0] * x + R[1] * y + R[2] * zc + T[0];
    float gy = R[3] * x + R[4] * y + R[5] * zc + T[1];
    float gz = R[6] * x + R[7] * y + R[8] * zc + T[2];
    ek[16 + p * 3 + 0] = f2bf(gx);
    ek[16 + p * 3 + 1] = f2bf(gy);
    ek[16 + p * 3 + 2] = f2bf(gz);
    sk += gx * gx + gy * gy + gz * gz;
  }
#pragma unroll
  for (int d = 28; d < 32; ++d) { eq[d] = 0; ek[d] = 0; }
  mq[gid] = -0.5f * cg * sq;
  mk[gid] = -0.5f * cg * sk;

#pragma unroll
  for (int d = 0; d < CH; ++d)
    vT[(size_t)(h * CH + d) * Nn + i] = f2bf(Pi[384 + h * CH + d]);
#pragma unroll
  for (int p = 0; p < PV; ++p) {
    float x = Pi[864 + h * 24 + p * 3 + 0];
    float y = Pi[864 + h * 24 + p * 3 + 1];
    float zc = Pi[864 + h * 24 + p * 3 + 2];
    vpT[(size_t)(h * 24 + p * 3 + 0) * Nn + i] = f2bf(R[0] * x + R[1] * y + R[2] * zc + T[0]);
    vpT[(size_t)(h * 24 + p * 3 + 1) * Nn + i] = f2bf(R[3] * x + R[4] * y + R[5] * zc + T[1]);
    vpT[(size_t)(h * 24 + p * 3 + 2) * Nn + i] = f2bf(R[6] * x + R[7] * y + R[8] * zc + T[2]);
  }
}

// ===== K1c: Wb B-fragments (dense): wbf[kk][lane][e] for 16x16x32 MFMA ======
__global__ __launch_bounds__(256) void k_wbfrag(
    const float* __restrict__ Wb, ushort_t* __restrict__ wbf) {
  int t = threadIdx.x;            // 256 = 4 ksteps * 64 lanes
  int kk = t >> 6, l = t & 63;
  int h = l & 15, lk = l >> 4;
#pragma unroll
  for (int e = 0; e < 8; ++e) {
    int c = kk * 32 + lk * 8 + e;
    wbf[t * 8 + e] = (h < Hh) ? f2bf(Wb[c * Hh + h]) : (ushort_t)0;
  }
}

// ======== K2: fused flash, block per (i, j-half), 8 waves ====================
// Wave w owns 32 j's of its half. Partial output (unnormalized) + (M,L) -> pp.
// NOTE: launch_bounds min-waves = 4 (cap 128 VGPR). R10's =8 capped VGPR at 32
// and spilled acc[] to scratch -> 136us. 64 VGPR natively allows 8 waves/SIMD.
__global__ __launch_bounds__(512, 4) void k_fused4(
    const float* __restrict__ z, const ushort_t* __restrict__ eqb,
    const ushort_t* __restrict__ ekb, const ushort_t* __restrict__ wbf,
    const float* __restrict__ mk,
    const ushort_t* __restrict__ vT, const ushort_t* __restrict__ vpT,
    float* __restrict__ pp) {
  __shared__ float smemf[2336];                    // 9344 B
  char*  pB = (char*)smemf;                        // P: [16][256] u16, swizzled (8KB)
  float* mb = smemf + 2048;                        // [8][16]
  float* lb = smemf + 2176;                        // [8][16]
  float* Mv = smemf + 2304;                        // [16]

  int i = blockIdx.x, half = blockIdx.y, tid = threadIdx.x;
  int l = tid & 63, w = tid >> 6;                  // 8 waves
  int cl = l & 15, lk = l >> 4;
  int j0b = half * 256;
  float* po = pp + ((size_t)i * 2 + half) * 2048;
  const float* zb = z + (size_t)i * Nn * CZ;
  int swz = (cl & 7) << 4;

  bf16x8 zer;
#pragma unroll
  for (int e = 0; e < 8; ++e) zer[e] = 0;

  bf16x8 wbreg[4];
#pragma unroll
  for (int kk = 0; kk < 4; ++kk)
    wbreg[kk] = *(const bf16x8*)&wbf[(kk * 64 + l) * 8];
  bf16x8 eqsel = zer;
  if (cl < Hh) eqsel = *(const bf16x8*)&eqb[((size_t)i * Hh + cl) * 32 + lk * 8];

  // ---- Phase 1: logits for wave's 32 j (2 groups of 16) ----
  float v[2][4];
#pragma unroll
  for (int cg = 0; cg < 2; ++cg) {
    int jt = w * 32 + cg * 16;                     // local j base
    int jrow = j0b + jt + cl;                      // global j (A row)
    f32x4 dl = {0.f, 0.f, 0.f, 0.f};
#pragma unroll
    for (int kk = 0; kk < 4; ++kk) {
      const float4* zp = (const float4*)(zb + (size_t)jrow * CZ + (kk * 4 + lk) * 8);
      float4 x0 = zp[0], x1 = zp[1];
      bf16x8 a;
      a[0] = (short)f2bf(x0.x); a[1] = (short)f2bf(x0.y);
      a[2] = (short)f2bf(x0.z); a[3] = (short)f2bf(x0.w);
      a[4] = (short)f2bf(x1.x); a[5] = (short)f2bf(x1.y);
      a[6] = (short)f2bf(x1.z); a[7] = (short)f2bf(x1.w);
      dl = __builtin_amdgcn_mfma_f32_16x16x32_bf16(a, wbreg[kk], dl, 0, 0, 0);
    }
#pragma unroll
    for (int hp = 0; hp < Hh; ++hp) {
      bf16x8 a = *(const bf16x8*)&ekb[((size_t)jrow * Hh + hp) * 32 + lk * 8];
      bf16x8 b = (cl == hp) ? eqsel : zer;
      dl = __builtin_amdgcn_mfma_f32_16x16x32_bf16(a, b, dl, 0, 0, 0);
    }
    int jb = j0b + jt + lk * 4;                    // global j of D rows
    if (cl < Hh) {
#pragma unroll
      for (int r = 0; r < 4; ++r) v[cg][r] = W_L * (dl[r] + mk[(jb + r) * Hh + cl]);
    } else {
#pragma unroll
      for (int r = 0; r < 4; ++r) v[cg][r] = -1e30f;
    }
  }

  // ---- Phase 2: per-wave softmax over 32 j (head = cl) ----
  float m_w = v[0][0];
#pragma unroll
  for (int cg = 0; cg < 2; ++cg)
#pragma unroll
    for (int r = 0; r < 4; ++r) m_w = fmaxf(m_w, v[cg][r]);
  m_w = fmaxf(m_w, __shfl_xor(m_w, 16));
  m_w = fmaxf(m_w, __shfl_xor(m_w, 32));

  float ps = 0.f;
#pragma unroll
  for (int cg = 0; cg < 2; ++cg) {
    int j = w * 32 + cg * 16 + lk * 4;             // local j
    ushort_t p0 = f2bf(__expf(v[cg][0] - m_w));
    ushort_t p1 = f2bf(__expf(v[cg][1] - m_w));
    ushort_t p2 = f2bf(__expf(v[cg][2] - m_w));
    ushort_t p3 = f2bf(__expf(v[cg][3] - m_w));
    ps += bf2f(p0) + bf2f(p1) + bf2f(p2) + bf2f(p3);
    uint2 d;
    d.x = (unsigned int)p0 | ((unsigned int)p1 << 16);
    d.y = (unsigned int)p2 | ((unsigned int)p3 << 16);
    *(uint2*)&pB[(cl * 512 + j * 2) ^ swz] = d;
  }
  ps += __shfl_xor(ps, 16);
  ps += __shfl_xor(ps, 32);
  if (lk == 0) { mb[w * 16 + cl] = m_w; lb[w * 16 + cl] = ps; }
  __syncthreads();                                 // #1

  if (tid < 16) {
    float M = mb[tid];
#pragma unroll
    for (int ww = 1; ww < 8; ++ww) M = fmaxf(M, mb[ww * 16 + tid]);
    float L = 0.f;
#pragma unroll
    for (int ww = 0; ww < 8; ++ww) L += lb[ww * 16 + tid] * __expf(mb[ww * 16 + tid] - M);
    Mv[tid] = M;
    po[2016 + tid] = M;                            // per-head block max
    po[2032 + tid] = L;                            // per-head block sum
  }
  __syncthreads();                                 // #2

  // ---- Phase 3: rescale own P slice by exp(m_w - M_block) ----
  float sf = __expf(m_w - Mv[cl]);
#pragma unroll
  for (int q = 0; q < 2; ++q) {
    int j = w * 32 + lk * 8 + q * 4;               // local j
    unsigned int off = (unsigned int)(cl * 512 + j * 2) ^ swz;
    uint2 d = *(uint2*)&pB[off];
    ushort_t q0 = f2bf(bf2f((ushort_t)(d.x & 0xffff)) * sf);
    ushort_t q1 = f2bf(bf2f((ushort_t)(d.x >> 16)) * sf);
    ushort_t q2 = f2bf(bf2f((ushort_t)(d.y & 0xffff)) * sf);
    ushort_t q3 = f2bf(bf2f((ushort_t)(d.y >> 16)) * sf);
    d.x = (unsigned int)q0 | ((unsigned int)q1 << 16);
    d.y = (unsigned int)q2 | ((unsigned int)q3 << 16);
    *(uint2*)&pB[off] = d;
  }
  __syncthreads();                                 // #3

  // ---- Phase 4: attend over this half's 256 j, wave owns t = w + 8n ----
  f32x4 acc[5];
#pragma unroll
  for (int n = 0; n < 5; ++n) acc[n] = (f32x4){0.f, 0.f, 0.f, 0.f};

  for (int kk = 0; kk < 8; ++kk) {
    int koff = kk * 32 + lk * 8;                   // local j
    int jg = j0b + koff;                           // global j
    bf16x8 af = *(const bf16x8*)&pB[(cl * 512 + koff * 2) ^ swz];
#pragma unroll
    for (int n = 0; n < 5; ++n) {
      int t = w + n * 8;
      if (t < 38) {
        bf16x8 bfr;
        if (t < 8) {                               // o_pair: z^T from global/L2
          const float* zc = zb + (size_t)jg * CZ + t * 16 + cl;
#pragma unroll
          for (int e = 0; e < 8; ++e) bfr[e] = (short)f2bf(zc[e * CZ]);
        } else if (t < 20) {
          bfr = *(const bf16x8*)(vT + (size_t)((t - 8) * 16 + cl) * Nn + jg);
        } else {
          bfr = *(const bf16x8*)(vpT + (size_t)((t - 20) * 16 + cl) * Nn + jg);
        }
        acc[n] = __builtin_amdgcn_mfma_f32_16x16x32_bf16(af, bfr, acc[n], 0, 0, 0);
      }
    }
  }

  // ---- store raw partial acc (no normalization) ----
#pragma unroll
  for (int n = 0; n < 5; ++n) {
    int t = w + n * 8;
    if (t < 38) {
      if (t < 8) {
        int c = t * 16 + cl;
#pragma unroll
        for (int r = 0; r < 4; ++r) {
          int h = lk * 4 + r;
          if (h < Hh) po[h * CZ + c] = acc[n][r];
        }
      } else if (t < 20) {
        int h = t - 8;
        if (lk == (h >> 2)) po[1536 + h * CH + cl] = acc[n][h & 3];
      } else {
        int cp = (t - 20) * 16 + cl;
        int h = cp / 24;
        if (lk == (h >> 2)) po[1728 + cp] = acc[n][h & 3];
      }
    }
  }
}

// ======== K3: merge halves + normalize + invert-apply + norm -> feat16 ======
__global__ __launch_bounds__(256) void k_merge(
    const float* __restrict__ pp, const float* __restrict__ rot,
    const float* __restrict__ trans, ushort_t* __restrict__ feat16) {
  __shared__ float a0s[16], a1s[16];
  __shared__ float optg[288];
  int i = blockIdx.x, tid = threadIdx.x;
  const float* p0 = pp + ((size_t)i * 2 + 0) * 2048;
  const float* p1 = pp + ((size_t)i * 2 + 1) * 2048;
  ushort_t* Fi = feat16 + (size_t)i * FIN;

  if (tid < 16) {
    float m0 = p0[2016 + tid], m1 = p1[2016 + tid];
    float M = fmaxf(m0, m1);
    float s0 = __expf(m0 - M), s1 = __expf(m1 - M);
    float L = p0[2032 + tid] * s0 + p1[2032 + tid] * s1;
    float inv = (tid < Hh) ? 1.f / L : 0.f;
    a0s[tid] = s0 * inv;
    a1s[tid] = s1 * inv;
  }
  __syncthreads();

  for (int idx = tid; idx < 1728; idx += 256) {
    int h = (idx < 1536) ? (idx >> 7) : ((idx - 1536) >> 4);
    Fi[idx] = f2bf(p0[idx] * a0s[h] + p1[idx] * a1s[h]);
  }
  for (int idx = tid; idx < 288; idx += 256) {
    int h = idx / 24;
    optg[idx] = p0[1728 + idx] * a0s[h] + p1[1728 + idx] * a1s[h];
  }
  __syncthreads();

  if (tid < 96) {
    int h = tid >> 3, p = tid & 7;
    int cp = h * 24 + p * 3;
    float g0 = optg[cp + 0] - trans[i * 3 + 0];
    float g1 = optg[cp + 1] - trans[i * 3 + 1];
    float g2 = optg[cp + 2] - trans[i * 3 + 2];
    const float* R = rot + i * 9;
    float ss = 0.f;
#pragma unroll
    for (int nn2 = 0; nn2 < 3; ++nn2) {
      float o = R[nn2] * g0 + R[3 + nn2] * g1 + R[6 + nn2] * g2;   // R^T (g - t)
      Fi[1728 + cp + nn2] = f2bf(o);
      ss += o * o;
    }
    Fi[2016 + h * 8 + p] = f2bf(sqrtf(ss + 1e-12f));
  }
}

// ============ K5: out = feat16 @ WfT^T + bf (MFMA) ==========================
__global__ __launch_bounds__(64) void k_outm(
    const ushort_t* __restrict__ feat16, const ushort_t* __restrict__ WfT,
    const float* __restrict__ bfv, float* __restrict__ out) {
  int ot = blockIdx.x;                             // 0..23
  int i0 = blockIdx.y * 16;
  int l = threadIdx.x;
  int cl = l & 15, lk = l >> 4;
  f32x4 acc = {0.f, 0.f, 0.f, 0.f};
  const ushort_t* arow = feat16 + (size_t)(i0 + cl) * FIN;
  const ushort_t* brow = WfT + (size_t)(ot * 16 + cl) * FIN;
#pragma unroll 6
  for (int kk = 0; kk < 66; ++kk) {
    bf16x8 a = *(const bf16x8*)(arow + kk * 32 + lk * 8);
    bf16x8 b = *(const bf16x8*)(brow + kk * 32 + lk * 8);
    acc = __builtin_amdgcn_mfma_f32_16x16x32_bf16(a, b, acc, 0, 0, 0);
  }
  float bias = bfv[ot * 16 + cl];
#pragma unroll
  for (int r = 0; r < 4; ++r)
    out[(size_t)(i0 + lk * 4 + r) * CS + ot * 16 + cl] = acc[r] + bias;
}

// ============================ launcher ======================================
extern "C" void kernel_launch(void* const* d_in, const int* in_sizes, int n_in,
                              void* d_out, int out_size, void* d_ws, size_t ws_size,
                              hipStream_t stream) {
  const float* s_i   = (const float*)d_in[0];
  const float* z_ij  = (const float*)d_in[1];
  const float* rot   = (const float*)d_in[2];
  const float* trans = (const float*)d_in[3];
  const float* Wq    = (const float*)d_in[4];
  const float* Wk    = (const float*)d_in[5];
  const float* Wv    = (const float*)d_in[6];
  const float* Wqp   = (const float*)d_in[7];
  const float* Wkp   = (const float*)d_in[8];
  const float* Wvp   = (const float*)d_in[9];
  const float* Wb    = (const float*)d_in[10];
  const float* gamma = (const float*)d_in[11];
  const float* Wf    = (const float*)d_in[12];
  const float* bf    = (const float*)d_in[13];
  float* out = (float*)d_out;

  float* w = (float*)d_ws;
  float*    P    = w + OFF_P;
  float*    mq   = w + OFF_MQ;
  float*    mk   = w + OFF_MK;
  ushort_t* vT   = (ushort_t*)(w + OFF_VT);
  ushort_t* vpT  = (ushort_t*)(w + OFF_VPT);
  ushort_t* s16  = (ushort_t*)(w + OFF_S16);
  ushort_t* WcT  = (ushort_t*)(w + OFF_WCT);
  ushort_t* WfT  = (ushort_t*)(w + OFF_WFT);
  ushort_t* f16  = (ushort_t*)(w + OFF_F16);
  float*    pp   = w + OFF_PP;
  ushort_t* ekb  = (ushort_t*)(w + OFF_EKB);
  ushort_t* eqb  = (ushort_t*)(w + OFF_EQB);
  ushort_t* wbf  = (ushort_t*)(w + OFF_WBF);

  k_s16<<<768, 256, 0, stream>>>(s_i, s16);
  k_wcatT<<<1152, 384, 0, stream>>>(Wq, Wk, Wv, Wqp, Wkp, Wvp, WcT);
  k_wfT<<<384, 256, 0, stream>>>(Wf, WfT);
  k_projm<<<dim3(72, 32), 64, 0, stream>>>(s16, WcT, P);
  k_prep<<<96, 64, 0, stream>>>(P, rot, trans, gamma, eqb, ekb, mq, mk, vT, vpT);
  k_wbfrag<<<1, 256, 0, stream>>>(Wb, wbf);
  k_fused4<<<dim3(512, 2), 512, 0, stream>>>(z_ij, eqb, ekb, wbf, mk, vT, vpT, pp);
  k_merge<<<512, 256, 0, stream>>>(pp, rot, trans, f16);
  k_outm<<<dim3(24, 32), 64, 0, stream>>>(f16, WfT, bf, out);
}

// Round 12
// 110.266 us; speedup vs baseline: 1.3547x; 1.1814x over previous
//
#include <hip/hip_runtime.h>
#include <hip/hip_bf16.h>
#include <math.h>

#define Nn    512
#define CS    384
#define CZ    128
#define CH    16
#define Hh    12
#define PQ    4
#define PV    8
#define NCOL  1152   // 192*3 + 144*2 + 288
#define FIN   2112

#define W_C   0.23570226039551584f   // sqrt(2/(9*4))
#define W_L   0.5773502691896258f    // sqrt(1/3)

typedef unsigned short ushort_t;
typedef unsigned int uint_t;
typedef __attribute__((ext_vector_type(8))) short bf16x8;
typedef __attribute__((ext_vector_type(4))) float f32x4;

// ---------------- workspace layout (float offsets) ----------------
#define OFF_P      0u
#define OFF_MQ     589824u
#define OFF_MK     595968u
#define OFF_VT     602112u      // v16T  [192][512] bf16
#define OFF_VPT    651264u      // vpgT  [288][512] bf16
#define OFF_S16    1830912u     // s bf16 [512][384]      = 98304 floats
#define OFF_WCT    1929216u     // WcatT bf16 [1152][384] = 221184 floats
#define OFF_WFT    2150400u     // WfT bf16 [384][2112]   = 405504 floats
#define OFF_F16    2555904u     // feat bf16 [512][2112]  = 540672 floats (ends 3096576)
#define OFF_PP     3145728u     // partials [512][2][2048] f32 (ends 5242880)
#define OFF_EKD    5242880u     // ekd uint [14][6144] = 86016 (ends 5328896)
#define OFF_VFRAG  5328896u     // vfrag bf16 [30][16][64][8] = 122880 f (ends 5451776)
#define OFF_EQB    21854208u    // eqb bf16 [6144][32]
#define OFF_WBF    21952512u

__device__ inline ushort_t f2bf(float f) {
  __hip_bfloat16 h = __float2bfloat16(f);
  return *reinterpret_cast<ushort_t*>(&h);
}
__device__ inline float bf2f(ushort_t u) {
  unsigned int x = ((unsigned int)u) << 16;
  return __uint_as_float(x);
}

// ============ K0a: s_i -> bf16 ==============================================
__global__ __launch_bounds__(256) void k_s16(
    const float* __restrict__ s, ushort_t* __restrict__ s16) {
  int idx = blockIdx.x * 256 + threadIdx.x;        // < 196608
  s16[idx] = f2bf(s[idx]);
}

// ============ K0b: WcatT[col][k] bf16 from 6 weight arrays ==================
__global__ __launch_bounds__(384) void k_wcatT(
    const float* __restrict__ Wq, const float* __restrict__ Wk,
    const float* __restrict__ Wv, const float* __restrict__ Wqp,
    const float* __restrict__ Wkp, const float* __restrict__ Wvp,
    ushort_t* __restrict__ WcatT) {
  int col = blockIdx.x;                            // 0..1151
  int k = threadIdx.x;                             // 0..383
  float v;
  if      (col < 192)  v = Wq [k * 192 + col];
  else if (col < 384)  v = Wk [k * 192 + col - 192];
  else if (col < 576)  v = Wv [k * 192 + col - 384];
  else if (col < 720)  v = Wqp[k * 144 + col - 576];
  else if (col < 864)  v = Wkp[k * 144 + col - 720];
  else                 v = Wvp[k * 288 + col - 864];
  WcatT[(size_t)col * CS + k] = f2bf(v);
}

// ============ K0c: WfT[o][f] bf16 from Wf[f][o] =============================
__global__ __launch_bounds__(256) void k_wfT(
    const float* __restrict__ Wf, ushort_t* __restrict__ WfT) {
  int o = blockIdx.x;                              // 0..383
  for (int f = threadIdx.x; f < FIN; f += 256)
    WfT[(size_t)o * FIN + f] = f2bf(Wf[(size_t)f * CS + o]);
}

// ============ K1: proj via MFMA: P = s16 @ WcatT^T (f32 out) ================
__global__ __launch_bounds__(64) void k_projm(
    const ushort_t* __restrict__ s16, const ushort_t* __restrict__ WcatT,
    float* __restrict__ P) {
  int colt = blockIdx.x;                           // 0..71
  int i0 = blockIdx.y * 16;                        // 0..496
  int l = threadIdx.x;
  int cl = l & 15, lk = l >> 4;
  f32x4 acc = {0.f, 0.f, 0.f, 0.f};
  const ushort_t* arow = s16 + (size_t)(i0 + cl) * CS;
  const ushort_t* brow = WcatT + (size_t)(colt * 16 + cl) * CS;
#pragma unroll
  for (int kk = 0; kk < 12; ++kk) {
    bf16x8 a = *(const bf16x8*)(arow + kk * 32 + lk * 8);
    bf16x8 b = *(const bf16x8*)(brow + kk * 32 + lk * 8);
    acc = __builtin_amdgcn_mfma_f32_16x16x32_bf16(a, b, acc, 0, 0, 0);
  }
#pragma unroll
  for (int r = 0; r < 4; ++r)
    P[(size_t)(i0 + lk * 4 + r) * NCOL + colt * 16 + cl] = acc[r];
}

// ===== K1b: rigid transforms -> eqb bf16, ekd pair-major, mq/mk, vT, vpT ====
__global__ __launch_bounds__(64) void k_prep(
    const float* __restrict__ P, const float* __restrict__ rot,
    const float* __restrict__ trans, const float* __restrict__ gamma,
    ushort_t* __restrict__ eqb, uint_t* __restrict__ ekd,
    float* __restrict__ mq, float* __restrict__ mk,
    ushort_t* __restrict__ vT, ushort_t* __restrict__ vpT) {
  int gid = blockIdx.x * 64 + threadIdx.x;        // < 6144
  int i = gid / Hh, h = gid % Hh;
  const float* Pi = P + (size_t)i * NCOL;
  float R[9], T[3];
#pragma unroll
  for (int m = 0; m < 9; ++m) R[m] = rot[i * 9 + m];
#pragma unroll
  for (int m = 0; m < 3; ++m) T[m] = trans[i * 3 + m];
  float cg = W_C * gamma[h];

  ushort_t eql[32], ekl[32];
#pragma unroll
  for (int d = 0; d < CH; ++d) eql[d] = f2bf(Pi[h * CH + d] * 0.25f);  // q/sqrt(16)
#pragma unroll
  for (int d = 0; d < CH; ++d) ekl[d] = f2bf(Pi[192 + h * CH + d]);    // k
  float sq = 0.f, sk = 0.f;
#pragma unroll
  for (int p = 0; p < PQ; ++p) {
    float x = Pi[576 + h * 12 + p * 3 + 0];
    float y = Pi[576 + h * 12 + p * 3 + 1];
    float zc = Pi[576 + h * 12 + p * 3 + 2];
    float gx = R[0] * x + R[1] * y + R[2] * zc + T[0];
    float gy = R[3] * x + R[4] * y + R[5] * zc + T[1];
    float gz = R[6] * x + R[7] * y + R[8] * zc + T[2];
    eql[16 + p * 3 + 0] = f2bf(cg * gx);
    eql[16 + p * 3 + 1] = f2bf(cg * gy);
    eql[16 + p * 3 + 2] = f2bf(cg * gz);
    sq += gx * gx + gy * gy + gz * gz;
  }
#pragma unroll
  for (int p = 0; p < PQ; ++p) {
    float x = Pi[720 + h * 12 + p * 3 + 0];
    float y = Pi[720 + h * 12 + p * 3 + 1];
    float zc = Pi[720 + h * 12 + p * 3 + 2];
    float gx = R[0] * x + R[1] * y + R[2] * zc + T[0];
    float gy = R[3] * x + R[4] * y + R[5] * zc + T[1];
    float gz = R[6] * x + R[7] * y + R[8] * zc + T[2];
    ekl[16 + p * 3 + 0] = f2bf(gx);
    ekl[16 + p * 3 + 1] = f2bf(gy);
    ekl[16 + p * 3 + 2] = f2bf(gz);
    sk += gx * gx + gy * gy + gz * gz;
  }
#pragma unroll
  for (int d = 28; d < 32; ++d) { eql[d] = 0; ekl[d] = 0; }

  ushort_t* eq = eqb + (size_t)gid * 32;
#pragma unroll
  for (int d = 0; d < 32; ++d) eq[d] = eql[d];
  // ekd: pair-major (j*12+h) with 2 bf16 dims per dword
#pragma unroll
  for (int d2 = 0; d2 < 14; ++d2)
    ekd[d2 * 6144 + gid] = (uint_t)ekl[2 * d2] | ((uint_t)ekl[2 * d2 + 1] << 16);

  mq[gid] = -0.5f * cg * sq;
  mk[gid] = -0.5f * cg * sk;

#pragma unroll
  for (int d = 0; d < CH; ++d)
    vT[(size_t)(h * CH + d) * Nn + i] = f2bf(Pi[384 + h * CH + d]);
#pragma unroll
  for (int p = 0; p < PV; ++p) {
    float x = Pi[864 + h * 24 + p * 3 + 0];
    float y = Pi[864 + h * 24 + p * 3 + 1];
    float zc = Pi[864 + h * 24 + p * 3 + 2];
    vpT[(size_t)(h * 24 + p * 3 + 0) * Nn + i] = f2bf(R[0] * x + R[1] * y + R[2] * zc + T[0]);
    vpT[(size_t)(h * 24 + p * 3 + 1) * Nn + i] = f2bf(R[3] * x + R[4] * y + R[5] * zc + T[1]);
    vpT[(size_t)(h * 24 + p * 3 + 2) * Nn + i] = f2bf(R[6] * x + R[7] * y + R[8] * zc + T[2]);
  }
}

// ===== K1c: Wb B-fragments (dense): wbf[kk][lane][e] for 16x16x32 MFMA ======
__global__ __launch_bounds__(256) void k_wbfrag(
    const float* __restrict__ Wb, ushort_t* __restrict__ wbf) {
  int t = threadIdx.x;            // 256 = 4 ksteps * 64 lanes
  int kk = t >> 6, l = t & 63;
  int h = l & 15, lk = l >> 4;
#pragma unroll
  for (int e = 0; e < 8; ++e) {
    int c = kk * 32 + lk * 8 + e;
    wbf[t * 8 + e] = (h < Hh) ? f2bf(Wb[c * Hh + h]) : (ushort_t)0;
  }
}

// ===== K1d: pre-fragmented V: vfrag[tt][jblk][lane][8] (linear wave loads) ==
__global__ __launch_bounds__(64) void k_vfrag(
    const ushort_t* __restrict__ vT, const ushort_t* __restrict__ vpT,
    ushort_t* __restrict__ vfrag) {
  int tt = blockIdx.x;                             // 0..29 (t-8)
  int jb = blockIdx.y;                             // 0..15 (j/32)
  int l = threadIdx.x;
  int cl = l & 15, lk = l >> 4;
  const ushort_t* src = (tt < 12)
      ? vT  + (size_t)(tt * 16 + cl) * Nn
      : vpT + (size_t)((tt - 12) * 16 + cl) * Nn;
  bf16x8 v = *(const bf16x8*)(src + jb * 32 + lk * 8);
  *(bf16x8*)(vfrag + (((size_t)tt * 16 + jb) * 64 + l) * 8) = v;
}

// ======== K2: fused flash, block per (i, j-half), 8 waves ====================
// ext+mk via coalesced VALU pair-dots; zWb via MFMA; V via linear vfrag loads.
__global__ __launch_bounds__(512, 4) void k_fused5(
    const float* __restrict__ z, const ushort_t* __restrict__ eqb,
    const uint_t* __restrict__ ekd, const ushort_t* __restrict__ wbf,
    const float* __restrict__ mk, const ushort_t* __restrict__ vfrag,
    float* __restrict__ pp) {
  __shared__ float smemf[5560];                    // 22240 B
  char*   pB   = (char*)smemf;                     // P: [16][256] u16 swz (8KB)
  float*  extb = smemf + 2048;                     // [8][384] ext+mk
  uint_t* eqs  = (uint_t*)(smemf + 5120);          // [12][14] eq pairs
  float*  mb   = smemf + 5288;                     // [8][16]
  float*  lb   = smemf + 5416;                     // [8][16]
  float*  Mv   = smemf + 5544;                     // [16]

  int i = blockIdx.x, half = blockIdx.y, tid = threadIdx.x;
  int l = tid & 63, w = tid >> 6;                  // 8 waves
  int cl = l & 15, lk = l >> 4;
  int j0b = half * 256;
  float* po = pp + ((size_t)i * 2 + half) * 2048;
  const float* zb = z + (size_t)i * Nn * CZ;
  int swz = (cl & 7) << 4;

  // stage eq pair table (dword view of eqb row block for this i)
  if (tid < 168) {
    int h = tid / 14, d2 = tid - h * 14;
    eqs[h * 14 + d2] = ((const uint_t*)eqb)[i * 192 + h * 16 + d2];
  }
  __syncthreads();                                 // #0

  // ---- ext+mk via VALU: 6 rounds x 64 pairs (all loads coalesced) ----
  int base = (j0b + w * 32) * 12;
#pragma unroll
  for (int rd = 0; rd < 6; ++rd) {
    int idx = rd * 64 + l;                         // 0..383
    int jr = (idx * 683) >> 13;                    // idx / 12
    int h = idx - jr * 12;
    float e = mk[base + idx];
#pragma unroll
    for (int d2 = 0; d2 < 14; ++d2) {
      uint_t ev = ekd[d2 * 6144 + base + idx];
      uint_t qv = eqs[h * 14 + d2];
      e += __uint_as_float(ev << 16) * __uint_as_float(qv << 16)
         + __uint_as_float(ev & 0xffff0000u) * __uint_as_float(qv & 0xffff0000u);
    }
    extb[w * 384 + idx] = e;
  }

  bf16x8 wbreg[4];
#pragma unroll
  for (int kk = 0; kk < 4; ++kk)
    wbreg[kk] = *(const bf16x8*)&wbf[(kk * 64 + l) * 8];

  // ---- Phase 1: logits = zWb (MFMA) + extb; wave w owns 32 j ----
  float v[2][4];
#pragma unroll
  for (int cg = 0; cg < 2; ++cg) {
    int jrow = j0b + w * 32 + cg * 16 + cl;        // global j (A row)
    f32x4 dl = {0.f, 0.f, 0.f, 0.f};
#pragma unroll
    for (int kk = 0; kk < 4; ++kk) {
      const float4* zp = (const float4*)(zb + (size_t)jrow * CZ + (kk * 4 + lk) * 8);
      float4 x0 = zp[0], x1 = zp[1];
      bf16x8 a;
      a[0] = (short)f2bf(x0.x); a[1] = (short)f2bf(x0.y);
      a[2] = (short)f2bf(x0.z); a[3] = (short)f2bf(x0.w);
      a[4] = (short)f2bf(x1.x); a[5] = (short)f2bf(x1.y);
      a[6] = (short)f2bf(x1.z); a[7] = (short)f2bf(x1.w);
      dl = __builtin_amdgcn_mfma_f32_16x16x32_bf16(a, wbreg[kk], dl, 0, 0, 0);
    }
    if (cl < Hh) {
#pragma unroll
      for (int r = 0; r < 4; ++r)
        v[cg][r] = W_L * (dl[r] + extb[w * 384 + (cg * 16 + lk * 4 + r) * 12 + cl]);
    } else {
#pragma unroll
      for (int r = 0; r < 4; ++r) v[cg][r] = -1e30f;
    }
  }

  // ---- Phase 2: per-wave softmax over 32 j (head = cl) ----
  float m_w = v[0][0];
#pragma unroll
  for (int cg = 0; cg < 2; ++cg)
#pragma unroll
    for (int r = 0; r < 4; ++r) m_w = fmaxf(m_w, v[cg][r]);
  m_w = fmaxf(m_w, __shfl_xor(m_w, 16));
  m_w = fmaxf(m_w, __shfl_xor(m_w, 32));

  float ps = 0.f;
#pragma unroll
  for (int cg = 0; cg < 2; ++cg) {
    int j = w * 32 + cg * 16 + lk * 4;             // local j
    ushort_t p0 = f2bf(__expf(v[cg][0] - m_w));
    ushort_t p1 = f2bf(__expf(v[cg][1] - m_w));
    ushort_t p2 = f2bf(__expf(v[cg][2] - m_w));
    ushort_t p3 = f2bf(__expf(v[cg][3] - m_w));
    ps += bf2f(p0) + bf2f(p1) + bf2f(p2) + bf2f(p3);
    uint2 d;
    d.x = (uint_t)p0 | ((uint_t)p1 << 16);
    d.y = (uint_t)p2 | ((uint_t)p3 << 16);
    *(uint2*)&pB[(cl * 512 + j * 2) ^ swz] = d;
  }
  ps += __shfl_xor(ps, 16);
  ps += __shfl_xor(ps, 32);
  if (lk == 0) { mb[w * 16 + cl] = m_w; lb[w * 16 + cl] = ps; }
  __syncthreads();                                 // #1

  if (tid < 16) {
    float M = mb[tid];
#pragma unroll
    for (int ww = 1; ww < 8; ++ww) M = fmaxf(M, mb[ww * 16 + tid]);
    float L = 0.f;
#pragma unroll
    for (int ww = 0; ww < 8; ++ww) L += lb[ww * 16 + tid] * __expf(mb[ww * 16 + tid] - M);
    Mv[tid] = M;
    po[2016 + tid] = M;                            // per-head block max
    po[2032 + tid] = L;                            // per-head block sum
  }
  __syncthreads();                                 // #2

  // ---- Phase 3: rescale own P slice by exp(m_w - M_block) ----
  float sf = __expf(m_w - Mv[cl]);
#pragma unroll
  for (int q = 0; q < 2; ++q) {
    int j = w * 32 + lk * 8 + q * 4;               // local j
    uint_t off = (uint_t)(cl * 512 + j * 2) ^ swz;
    uint2 d = *(uint2*)&pB[off];
    ushort_t q0 = f2bf(bf2f((ushort_t)(d.x & 0xffff)) * sf);
    ushort_t q1 = f2bf(bf2f((ushort_t)(d.x >> 16)) * sf);
    ushort_t q2 = f2bf(bf2f((ushort_t)(d.y & 0xffff)) * sf);
    ushort_t q3 = f2bf(bf2f((ushort_t)(d.y >> 16)) * sf);
    d.x = (uint_t)q0 | ((uint_t)q1 << 16);
    d.y = (uint_t)q2 | ((uint_t)q3 << 16);
    *(uint2*)&pB[off] = d;
  }
  __syncthreads();                                 // #3

  // ---- Phase 4: attend over this half's 256 j, wave owns t = w + 8n ----
  f32x4 acc[5];
#pragma unroll
  for (int n = 0; n < 5; ++n) acc[n] = (f32x4){0.f, 0.f, 0.f, 0.f};

  for (int kk = 0; kk < 8; ++kk) {
    int koff = kk * 32 + lk * 8;                   // local j
    int jg = j0b + koff;                           // global j
    bf16x8 af = *(const bf16x8*)&pB[(cl * 512 + koff * 2) ^ swz];
#pragma unroll
    for (int n = 0; n < 5; ++n) {
      int t = w + n * 8;
      if (t < 38) {
        bf16x8 bfr;
        if (t < 8) {                               // o_pair: z^T from global/L3
          const float* zc = zb + (size_t)jg * CZ + t * 16 + cl;
#pragma unroll
          for (int e = 0; e < 8; ++e) bfr[e] = (short)f2bf(zc[e * CZ]);
        } else {                                   // linear pre-fragmented V
          bfr = *(const bf16x8*)(vfrag +
                (((size_t)(t - 8) * 16 + (half * 8 + kk)) * 64 + l) * 8);
        }
        acc[n] = __builtin_amdgcn_mfma_f32_16x16x32_bf16(af, bfr, acc[n], 0, 0, 0);
      }
    }
  }

  // ---- store raw partial acc (no normalization) ----
#pragma unroll
  for (int n = 0; n < 5; ++n) {
    int t = w + n * 8;
    if (t < 38) {
      if (t < 8) {
        int c = t * 16 + cl;
#pragma unroll
        for (int r = 0; r < 4; ++r) {
          int h = lk * 4 + r;
          if (h < Hh) po[h * CZ + c] = acc[n][r];
        }
      } else if (t < 20) {
        int h = t - 8;
        if (lk == (h >> 2)) po[1536 + h * CH + cl] = acc[n][h & 3];
      } else {
        int cp = (t - 20) * 16 + cl;
        int h = cp / 24;
        if (lk == (h >> 2)) po[1728 + cp] = acc[n][h & 3];
      }
    }
  }
}

// ======== K3: merge halves + normalize + invert-apply + norm -> feat16 ======
__global__ __launch_bounds__(256) void k_merge(
    const float* __restrict__ pp, const float* __restrict__ rot,
    const float* __restrict__ trans, ushort_t* __restrict__ feat16) {
  __shared__ float a0s[16], a1s[16];
  __shared__ float optg[288];
  int i = blockIdx.x, tid = threadIdx.x;
  const float* p0 = pp + ((size_t)i * 2 + 0) * 2048;
  const float* p1 = pp + ((size_t)i * 2 + 1) * 2048;
  ushort_t* Fi = feat16 + (size_t)i * FIN;

  if (tid < 16) {
    float m0 = p0[2016 + tid], m1 = p1[2016 + tid];
    float M = fmaxf(m0, m1);
    float s0 = __expf(m0 - M), s1 = __expf(m1 - M);
    float L = p0[2032 + tid] * s0 + p1[2032 + tid] * s1;
    float inv = (tid < Hh) ? 1.f / L : 0.f;
    a0s[tid] = s0 * inv;
    a1s[tid] = s1 * inv;
  }
  __syncthreads();

  for (int idx = tid; idx < 1728; idx += 256) {
    int h = (idx < 1536) ? (idx >> 7) : ((idx - 1536) >> 4);
    Fi[idx] = f2bf(p0[idx] * a0s[h] + p1[idx] * a1s[h]);
  }
  for (int idx = tid; idx < 288; idx += 256) {
    int h = idx / 24;
    optg[idx] = p0[1728 + idx] * a0s[h] + p1[1728 + idx] * a1s[h];
  }
  __syncthreads();

  if (tid < 96) {
    int h = tid >> 3, p = tid & 7;
    int cp = h * 24 + p * 3;
    float g0 = optg[cp + 0] - trans[i * 3 + 0];
    float g1 = optg[cp + 1] - trans[i * 3 + 1];
    float g2 = optg[cp + 2] - trans[i * 3 + 2];
    const float* R = rot + i * 9;
    float ss = 0.f;
#pragma unroll
    for (int nn2 = 0; nn2 < 3; ++nn2) {
      float o = R[nn2] * g0 + R[3 + nn2] * g1 + R[6 + nn2] * g2;   // R^T (g - t)
      Fi[1728 + cp + nn2] = f2bf(o);
      ss += o * o;
    }
    Fi[2016 + h * 8 + p] = f2bf(sqrtf(ss + 1e-12f));
  }
}

// ============ K5: out = feat16 @ WfT^T + bf (MFMA) ==========================
__global__ __launch_bounds__(64) void k_outm(
    const ushort_t* __restrict__ feat16, const ushort_t* __restrict__ WfT,
    const float* __restrict__ bfv, float* __restrict__ out) {
  int ot = blockIdx.x;                             // 0..23
  int i0 = blockIdx.y * 16;
  int l = threadIdx.x;
  int cl = l & 15, lk = l >> 4;
  f32x4 acc = {0.f, 0.f, 0.f, 0.f};
  const ushort_t* arow = feat16 + (size_t)(i0 + cl) * FIN;
  const ushort_t* brow = WfT + (size_t)(ot * 16 + cl) * FIN;
#pragma unroll 6
  for (int kk = 0; kk < 66; ++kk) {
    bf16x8 a = *(const bf16x8*)(arow + kk * 32 + lk * 8);
    bf16x8 b = *(const bf16x8*)(brow + kk * 32 + lk * 8);
    acc = __builtin_amdgcn_mfma_f32_16x16x32_bf16(a, b, acc, 0, 0, 0);
  }
  float bias = bfv[ot * 16 + cl];
#pragma unroll
  for (int r = 0; r < 4; ++r)
    out[(size_t)(i0 + lk * 4 + r) * CS + ot * 16 + cl] = acc[r] + bias;
}

// ============================ launcher ======================================
extern "C" void kernel_launch(void* const* d_in, const int* in_sizes, int n_in,
                              void* d_out, int out_size, void* d_ws, size_t ws_size,
                              hipStream_t stream) {
  const float* s_i   = (const float*)d_in[0];
  const float* z_ij  = (const float*)d_in[1];
  const float* rot   = (const float*)d_in[2];
  const float* trans = (const float*)d_in[3];
  const float* Wq    = (const float*)d_in[4];
  const float* Wk    = (const float*)d_in[5];
  const float* Wv    = (const float*)d_in[6];
  const float* Wqp   = (const float*)d_in[7];
  const float* Wkp   = (const float*)d_in[8];
  const float* Wvp   = (const float*)d_in[9];
  const float* Wb    = (const float*)d_in[10];
  const float* gamma = (const float*)d_in[11];
  const float* Wf    = (const float*)d_in[12];
  const float* bf    = (const float*)d_in[13];
  float* out = (float*)d_out;

  float* w = (float*)d_ws;
  float*    P     = w + OFF_P;
  float*    mq    = w + OFF_MQ;
  float*    mk    = w + OFF_MK;
  ushort_t* vT    = (ushort_t*)(w + OFF_VT);
  ushort_t* vpT   = (ushort_t*)(w + OFF_VPT);
  ushort_t* s16   = (ushort_t*)(w + OFF_S16);
  ushort_t* WcT   = (ushort_t*)(w + OFF_WCT);
  ushort_t* WfT   = (ushort_t*)(w + OFF_WFT);
  ushort_t* f16   = (ushort_t*)(w + OFF_F16);
  float*    pp    = w + OFF_PP;
  uint_t*   ekd   = (uint_t*)(w + OFF_EKD);
  ushort_t* vfrag = (ushort_t*)(w + OFF_VFRAG);
  ushort_t* eqb   = (ushort_t*)(w + OFF_EQB);
  ushort_t* wbf   = (ushort_t*)(w + OFF_WBF);

  k_s16<<<768, 256, 0, stream>>>(s_i, s16);
  k_wcatT<<<1152, 384, 0, stream>>>(Wq, Wk, Wv, Wqp, Wkp, Wvp, WcT);
  k_wfT<<<384, 256, 0, stream>>>(Wf, WfT);
  k_projm<<<dim3(72, 32), 64, 0, stream>>>(s16, WcT, P);
  k_prep<<<96, 64, 0, stream>>>(P, rot, trans, gamma, eqb, ekd, mq, mk, vT, vpT);
  k_wbfrag<<<1, 256, 0, stream>>>(Wb, wbf);
  k_vfrag<<<dim3(30, 16), 64, 0, stream>>>(vT, vpT, vfrag);
  k_fused5<<<dim3(512, 2), 512, 0, stream>>>(z_ij, eqb, ekd, wbf, mk, vfrag, pp);
  k_merge<<<512, 256, 0, stream>>>(pp, rot, trans, f16);
  k_outm<<<dim3(24, 32), 64, 0, stream>>>(f16, WfT, bf, out);
}

// Round 13
// 108.174 us; speedup vs baseline: 1.3809x; 1.0193x over previous
//
#include <hip/hip_runtime.h>
#include <hip/hip_bf16.h>
#include <math.h>

#define Nn    512
#define CS    384
#define CZ    128
#define CH    16
#define Hh    12
#define PQ    4
#define PV    8
#define NCOL  1152   // 192*3 + 144*2 + 288
#define FIN   2112

#define W_C   0.23570226039551584f   // sqrt(2/(9*4))
#define W_L   0.5773502691896258f    // sqrt(1/3)

typedef unsigned short ushort_t;
typedef unsigned int uint_t;
typedef __attribute__((ext_vector_type(8))) short bf16x8;
typedef __attribute__((ext_vector_type(4))) float f32x4;

// ---------------- workspace layout (float offsets) ----------------
#define OFF_P      0u
#define OFF_MQ     589824u
#define OFF_MK     595968u
#define OFF_VT     602112u      // v16T  [192][512] bf16
#define OFF_VPT    651264u      // vpgT  [288][512] bf16
#define OFF_S16    1830912u     // s bf16 [512][384]      = 98304 floats
#define OFF_WCT    1929216u     // WcatT bf16 [1152][384] = 221184 floats
#define OFF_WFT    2150400u     // WfT bf16 [384][2112]   = 405504 floats
#define OFF_F16    2555904u     // feat bf16 [512][2112]  = 540672 floats (ends 3096576)
#define OFF_PP     3145728u     // partials [512][2][2048] f32 (ends 5242880)
#define OFF_EKD    5242880u     // ekd uint [14][6144] = 86016 (ends 5328896)
#define OFF_VFRAG  5328896u     // vfrag bf16 [30][16][64][8] = 122880 f (ends 5451776)
#define OFF_EQB    21854208u    // eqb bf16 [6144][32]
#define OFF_WBF    21952512u

__device__ inline ushort_t f2bf(float f) {
  __hip_bfloat16 h = __float2bfloat16(f);
  return *reinterpret_cast<ushort_t*>(&h);
}
__device__ inline float bf2f(ushort_t u) {
  unsigned int x = ((unsigned int)u) << 16;
  return __uint_as_float(x);
}

// ============ K0a: s_i -> bf16 ==============================================
__global__ __launch_bounds__(256) void k_s16(
    const float* __restrict__ s, ushort_t* __restrict__ s16) {
  int idx = blockIdx.x * 256 + threadIdx.x;        // < 196608
  s16[idx] = f2bf(s[idx]);
}

// ============ K0b: WcatT[col][k] bf16 from 6 weight arrays ==================
__global__ __launch_bounds__(384) void k_wcatT(
    const float* __restrict__ Wq, const float* __restrict__ Wk,
    const float* __restrict__ Wv, const float* __restrict__ Wqp,
    const float* __restrict__ Wkp, const float* __restrict__ Wvp,
    ushort_t* __restrict__ WcatT) {
  int col = blockIdx.x;                            // 0..1151
  int k = threadIdx.x;                             // 0..383
  float v;
  if      (col < 192)  v = Wq [k * 192 + col];
  else if (col < 384)  v = Wk [k * 192 + col - 192];
  else if (col < 576)  v = Wv [k * 192 + col - 384];
  else if (col < 720)  v = Wqp[k * 144 + col - 576];
  else if (col < 864)  v = Wkp[k * 144 + col - 720];
  else                 v = Wvp[k * 288 + col - 864];
  WcatT[(size_t)col * CS + k] = f2bf(v);
}

// ============ K0c: WfT[o][f] bf16 from Wf[f][o] =============================
__global__ __launch_bounds__(256) void k_wfT(
    const float* __restrict__ Wf, ushort_t* __restrict__ WfT) {
  int o = blockIdx.x;                              // 0..383
  for (int f = threadIdx.x; f < FIN; f += 256)
    WfT[(size_t)o * FIN + f] = f2bf(Wf[(size_t)f * CS + o]);
}

// ============ K1: proj via MFMA: P = s16 @ WcatT^T (f32 out) ================
__global__ __launch_bounds__(64) void k_projm(
    const ushort_t* __restrict__ s16, const ushort_t* __restrict__ WcatT,
    float* __restrict__ P) {
  int colt = blockIdx.x;                           // 0..71
  int i0 = blockIdx.y * 16;                        // 0..496
  int l = threadIdx.x;
  int cl = l & 15, lk = l >> 4;
  f32x4 acc = {0.f, 0.f, 0.f, 0.f};
  const ushort_t* arow = s16 + (size_t)(i0 + cl) * CS;
  const ushort_t* brow = WcatT + (size_t)(colt * 16 + cl) * CS;
#pragma unroll
  for (int kk = 0; kk < 12; ++kk) {
    bf16x8 a = *(const bf16x8*)(arow + kk * 32 + lk * 8);
    bf16x8 b = *(const bf16x8*)(brow + kk * 32 + lk * 8);
    acc = __builtin_amdgcn_mfma_f32_16x16x32_bf16(a, b, acc, 0, 0, 0);
  }
#pragma unroll
  for (int r = 0; r < 4; ++r)
    P[(size_t)(i0 + lk * 4 + r) * NCOL + colt * 16 + cl] = acc[r];
}

// ===== K1b: rigid transforms -> eqb bf16, ekd pair-major, mq/mk, vT, vpT ====
__global__ __launch_bounds__(64) void k_prep(
    const float* __restrict__ P, const float* __restrict__ rot,
    const float* __restrict__ trans, const float* __restrict__ gamma,
    ushort_t* __restrict__ eqb, uint_t* __restrict__ ekd,
    float* __restrict__ mq, float* __restrict__ mk,
    ushort_t* __restrict__ vT, ushort_t* __restrict__ vpT) {
  int gid = blockIdx.x * 64 + threadIdx.x;        // < 6144
  int i = gid / Hh, h = gid % Hh;
  const float* Pi = P + (size_t)i * NCOL;
  float R[9], T[3];
#pragma unroll
  for (int m = 0; m < 9; ++m) R[m] = rot[i * 9 + m];
#pragma unroll
  for (int m = 0; m < 3; ++m) T[m] = trans[i * 3 + m];
  float cg = W_C * gamma[h];

  ushort_t eql[32], ekl[32];
#pragma unroll
  for (int d = 0; d < CH; ++d) eql[d] = f2bf(Pi[h * CH + d] * 0.25f);  // q/sqrt(16)
#pragma unroll
  for (int d = 0; d < CH; ++d) ekl[d] = f2bf(Pi[192 + h * CH + d]);    // k
  float sq = 0.f, sk = 0.f;
#pragma unroll
  for (int p = 0; p < PQ; ++p) {
    float x = Pi[576 + h * 12 + p * 3 + 0];
    float y = Pi[576 + h * 12 + p * 3 + 1];
    float zc = Pi[576 + h * 12 + p * 3 + 2];
    float gx = R[0] * x + R[1] * y + R[2] * zc + T[0];
    float gy = R[3] * x + R[4] * y + R[5] * zc + T[1];
    float gz = R[6] * x + R[7] * y + R[8] * zc + T[2];
    eql[16 + p * 3 + 0] = f2bf(cg * gx);
    eql[16 + p * 3 + 1] = f2bf(cg * gy);
    eql[16 + p * 3 + 2] = f2bf(cg * gz);
    sq += gx * gx + gy * gy + gz * gz;
  }
#pragma unroll
  for (int p = 0; p < PQ; ++p) {
    float x = Pi[720 + h * 12 + p * 3 + 0];
    float y = Pi[720 + h * 12 + p * 3 + 1];
    float zc = Pi[720 + h * 12 + p * 3 + 2];
    float gx = R[0] * x + R[1] * y + R[2] * zc + T[0];
    float gy = R[3] * x + R[4] * y + R[5] * zc + T[1];
    float gz = R[6] * x + R[7] * y + R[8] * zc + T[2];
    ekl[16 + p * 3 + 0] = f2bf(gx);
    ekl[16 + p * 3 + 1] = f2bf(gy);
    ekl[16 + p * 3 + 2] = f2bf(gz);
    sk += gx * gx + gy * gy + gz * gz;
  }
#pragma unroll
  for (int d = 28; d < 32; ++d) { eql[d] = 0; ekl[d] = 0; }

  ushort_t* eq = eqb + (size_t)gid * 32;
#pragma unroll
  for (int d = 0; d < 32; ++d) eq[d] = eql[d];
  // ekd: pair-major (j*12+h) with 2 bf16 dims per dword
#pragma unroll
  for (int d2 = 0; d2 < 14; ++d2)
    ekd[d2 * 6144 + gid] = (uint_t)ekl[2 * d2] | ((uint_t)ekl[2 * d2 + 1] << 16);

  mq[gid] = -0.5f * cg * sq;
  mk[gid] = -0.5f * cg * sk;

#pragma unroll
  for (int d = 0; d < CH; ++d)
    vT[(size_t)(h * CH + d) * Nn + i] = f2bf(Pi[384 + h * CH + d]);
#pragma unroll
  for (int p = 0; p < PV; ++p) {
    float x = Pi[864 + h * 24 + p * 3 + 0];
    float y = Pi[864 + h * 24 + p * 3 + 1];
    float zc = Pi[864 + h * 24 + p * 3 + 2];
    vpT[(size_t)(h * 24 + p * 3 + 0) * Nn + i] = f2bf(R[0] * x + R[1] * y + R[2] * zc + T[0]);
    vpT[(size_t)(h * 24 + p * 3 + 1) * Nn + i] = f2bf(R[3] * x + R[4] * y + R[5] * zc + T[1]);
    vpT[(size_t)(h * 24 + p * 3 + 2) * Nn + i] = f2bf(R[6] * x + R[7] * y + R[8] * zc + T[2]);
  }
}

// ===== K1c: Wb B-fragments (dense): wbf[kk][lane][e] for 16x16x32 MFMA ======
__global__ __launch_bounds__(256) void k_wbfrag(
    const float* __restrict__ Wb, ushort_t* __restrict__ wbf) {
  int t = threadIdx.x;            // 256 = 4 ksteps * 64 lanes
  int kk = t >> 6, l = t & 63;
  int h = l & 15, lk = l >> 4;
#pragma unroll
  for (int e = 0; e < 8; ++e) {
    int c = kk * 32 + lk * 8 + e;
    wbf[t * 8 + e] = (h < Hh) ? f2bf(Wb[c * Hh + h]) : (ushort_t)0;
  }
}

// ===== K1d: pre-fragmented V: vfrag[tt][jblk][lane][8] (linear wave loads) ==
__global__ __launch_bounds__(64) void k_vfrag(
    const ushort_t* __restrict__ vT, const ushort_t* __restrict__ vpT,
    ushort_t* __restrict__ vfrag) {
  int tt = blockIdx.x;                             // 0..29 (t-8)
  int jb = blockIdx.y;                             // 0..15 (j/32)
  int l = threadIdx.x;
  int cl = l & 15, lk = l >> 4;
  const ushort_t* src = (tt < 12)
      ? vT  + (size_t)(tt * 16 + cl) * Nn
      : vpT + (size_t)((tt - 12) * 16 + cl) * Nn;
  bf16x8 v = *(const bf16x8*)(src + jb * 32 + lk * 8);
  *(bf16x8*)(vfrag + (((size_t)tt * 16 + jb) * 64 + l) * 8) = v;
}

// ======== K2: fused flash, block per (i, j-half); z-half staged in LDS =======
// Stage 256x128 z tile f32->bf16 into 64KB swizzled LDS (16 indep loads/thread)
// Phase 1 A-frags and phase-4 o_pair B-frags both served from LDS.
__global__ __launch_bounds__(512, 4) void k_fused6(
    const float* __restrict__ z, const ushort_t* __restrict__ eqb,
    const uint_t* __restrict__ ekd, const ushort_t* __restrict__ wbf,
    const float* __restrict__ mk, const ushort_t* __restrict__ vfrag,
    float* __restrict__ pp) {
  __shared__ float smemf[19896];                   // 79584 B -> 2 blocks/CU
  char*   ztc  = (char*)smemf;                     // z tile [256][128] bf16 swz (64KB)
  float*  extb = smemf + 16384;                    // [8][384] f32 (12KB)...
  char*   pB   = (char*)(smemf + 16384);           // ...aliased by P [16][256] u16 swz
  uint_t* eqs  = (uint_t*)(smemf + 19456);         // [12][14]
  float*  mb   = smemf + 19624;                    // [8][16]
  float*  lb   = smemf + 19752;                    // [8][16]
  float*  Mv   = smemf + 19880;                    // [16]

  int i = blockIdx.x, half = blockIdx.y, tid = threadIdx.x;
  int l = tid & 63, w = tid >> 6;                  // 8 waves
  int cl = l & 15, lk = l >> 4;
  int j0b = half * 256;
  float* po = pp + ((size_t)i * 2 + half) * 2048;
  int swz = (cl & 7) << 4;

  // stage eq pair table
  if (tid < 168) {
    int h = tid / 14, d2 = tid - h * 14;
    eqs[h * 14 + d2] = ((const uint_t*)eqb)[i * 192 + h * 16 + d2];
  }
  __syncthreads();                                 // #0 eqs ready

  // ---- stage z half-tile: 16 independent float4 loads per thread ----
  {
    const float4* zg4 = (const float4*)(z + ((size_t)i * Nn + j0b) * CZ);
#pragma unroll
    for (int it = 0; it < 16; ++it) {
      int idx = it * 512 + tid;                    // 0..8191
      int row = idx >> 5, c4 = idx & 31;
      float4 x = zg4[idx];
      uint2 pk;
      pk.x = (uint_t)f2bf(x.x) | ((uint_t)f2bf(x.y) << 16);
      pk.y = (uint_t)f2bf(x.z) | ((uint_t)f2bf(x.w) << 16);
      *(uint2*)&ztc[row * 256 + ((c4 * 8) ^ ((row & 7) << 4))] = pk;
    }
  }

  // ---- ext+mk via VALU: 6 rounds x 64 pairs (coalesced; own extb region) ----
  {
    int base = (j0b + w * 32) * 12;
#pragma unroll
    for (int rd = 0; rd < 6; ++rd) {
      int idx = rd * 64 + l;                       // 0..383
      int jr = (idx * 683) >> 13;                  // idx / 12
      int h = idx - jr * 12;
      float e = mk[base + idx];
#pragma unroll
      for (int d2 = 0; d2 < 14; ++d2) {
        uint_t ev = ekd[d2 * 6144 + base + idx];
        uint_t qv = eqs[h * 14 + d2];
        e += __uint_as_float(ev << 16) * __uint_as_float(qv << 16)
           + __uint_as_float(ev & 0xffff0000u) * __uint_as_float(qv & 0xffff0000u);
      }
      extb[w * 384 + idx] = e;
    }
  }
  __syncthreads();                                 // #1 zt staged

  bf16x8 wbreg[4];
#pragma unroll
  for (int kk = 0; kk < 4; ++kk)
    wbreg[kk] = *(const bf16x8*)&wbf[(kk * 64 + l) * 8];

  // ---- Phase 1: logits = zWb (MFMA, A from LDS) + extb ----
  float v[2][4];
#pragma unroll
  for (int cg = 0; cg < 2; ++cg) {
    int jloc = w * 32 + cg * 16 + cl;              // local j (A row); jloc&7==cl&7
    f32x4 dl = {0.f, 0.f, 0.f, 0.f};
#pragma unroll
    for (int kk = 0; kk < 4; ++kk) {
      bf16x8 a = *(const bf16x8*)&ztc[jloc * 256 + ((kk * 64 + lk * 16) ^ ((cl & 7) << 4))];
      dl = __builtin_amdgcn_mfma_f32_16x16x32_bf16(a, wbreg[kk], dl, 0, 0, 0);
    }
    if (cl < Hh) {
#pragma unroll
      for (int r = 0; r < 4; ++r)
        v[cg][r] = W_L * (dl[r] + extb[w * 384 + (cg * 16 + lk * 4 + r) * 12 + cl]);
    } else {
#pragma unroll
      for (int r = 0; r < 4; ++r) v[cg][r] = -1e30f;
    }
  }
  __syncthreads();                                 // #2 extb dead -> pB writable

  // ---- Phase 2: per-wave softmax over 32 j (head = cl) ----
  float m_w = v[0][0];
#pragma unroll
  for (int cg = 0; cg < 2; ++cg)
#pragma unroll
    for (int r = 0; r < 4; ++r) m_w = fmaxf(m_w, v[cg][r]);
  m_w = fmaxf(m_w, __shfl_xor(m_w, 16));
  m_w = fmaxf(m_w, __shfl_xor(m_w, 32));

  float ps = 0.f;
#pragma unroll
  for (int cg = 0; cg < 2; ++cg) {
    int j = w * 32 + cg * 16 + lk * 4;             // local j
    ushort_t p0 = f2bf(__expf(v[cg][0] - m_w));
    ushort_t p1 = f2bf(__expf(v[cg][1] - m_w));
    ushort_t p2 = f2bf(__expf(v[cg][2] - m_w));
    ushort_t p3 = f2bf(__expf(v[cg][3] - m_w));
    ps += bf2f(p0) + bf2f(p1) + bf2f(p2) + bf2f(p3);
    uint2 d;
    d.x = (uint_t)p0 | ((uint_t)p1 << 16);
    d.y = (uint_t)p2 | ((uint_t)p3 << 16);
    *(uint2*)&pB[(cl * 512 + j * 2) ^ swz] = d;
  }
  ps += __shfl_xor(ps, 16);
  ps += __shfl_xor(ps, 32);
  if (lk == 0) { mb[w * 16 + cl] = m_w; lb[w * 16 + cl] = ps; }
  __syncthreads();                                 // #3

  if (tid < 16) {
    float M = mb[tid];
#pragma unroll
    for (int ww = 1; ww < 8; ++ww) M = fmaxf(M, mb[ww * 16 + tid]);
    float L = 0.f;
#pragma unroll
    for (int ww = 0; ww < 8; ++ww) L += lb[ww * 16 + tid] * __expf(mb[ww * 16 + tid] - M);
    Mv[tid] = M;
    po[2016 + tid] = M;                            // per-head block max
    po[2032 + tid] = L;                            // per-head block sum
  }
  __syncthreads();                                 // #4

  // ---- Phase 3: rescale own P slice by exp(m_w - M_block) ----
  float sf = __expf(m_w - Mv[cl]);
#pragma unroll
  for (int q = 0; q < 2; ++q) {
    int j = w * 32 + lk * 8 + q * 4;               // local j
    uint_t off = (uint_t)(cl * 512 + j * 2) ^ swz;
    uint2 d = *(uint2*)&pB[off];
    ushort_t q0 = f2bf(bf2f((ushort_t)(d.x & 0xffff)) * sf);
    ushort_t q1 = f2bf(bf2f((ushort_t)(d.x >> 16)) * sf);
    ushort_t q2 = f2bf(bf2f((ushort_t)(d.y & 0xffff)) * sf);
    ushort_t q3 = f2bf(bf2f((ushort_t)(d.y >> 16)) * sf);
    d.x = (uint_t)q0 | ((uint_t)q1 << 16);
    d.y = (uint_t)q2 | ((uint_t)q3 << 16);
    *(uint2*)&pB[off] = d;
  }
  __syncthreads();                                 // #5

  // ---- Phase 4: attend over this half's 256 j, wave owns t = w + 8n ----
  f32x4 acc[5];
#pragma unroll
  for (int n = 0; n < 5; ++n) acc[n] = (f32x4){0.f, 0.f, 0.f, 0.f};

  for (int kk = 0; kk < 8; ++kk) {
    int koff = kk * 32 + lk * 8;                   // local j
    bf16x8 af = *(const bf16x8*)&pB[(cl * 512 + koff * 2) ^ swz];
#pragma unroll
    for (int n = 0; n < 5; ++n) {
      int t = w + n * 8;
      if (t < 38) {
        bf16x8 bfr;
        if (t < 8) {                               // o_pair: z^T from LDS
#pragma unroll
          for (int e = 0; e < 8; ++e) {
            int rloc = koff + e;                   // rloc&7 == e
            bfr[e] = *(const short*)&ztc[rloc * 256 + ((t * 32 + cl * 2) ^ (e << 4))];
          }
        } else {                                   // linear pre-fragmented V
          bfr = *(const bf16x8*)(vfrag +
                (((size_t)(t - 8) * 16 + (half * 8 + kk)) * 64 + l) * 8);
        }
        acc[n] = __builtin_amdgcn_mfma_f32_16x16x32_bf16(af, bfr, acc[n], 0, 0, 0);
      }
    }
  }

  // ---- store raw partial acc (no normalization) ----
#pragma unroll
  for (int n = 0; n < 5; ++n) {
    int t = w + n * 8;
    if (t < 38) {
      if (t < 8) {
        int c = t * 16 + cl;
#pragma unroll
        for (int r = 0; r < 4; ++r) {
          int h = lk * 4 + r;
          if (h < Hh) po[h * CZ + c] = acc[n][r];
        }
      } else if (t < 20) {
        int h = t - 8;
        if (lk == (h >> 2)) po[1536 + h * CH + cl] = acc[n][h & 3];
      } else {
        int cp = (t - 20) * 16 + cl;
        int h = cp / 24;
        if (lk == (h >> 2)) po[1728 + cp] = acc[n][h & 3];
      }
    }
  }
}

// ======== K3: merge halves + normalize + invert-apply + norm -> feat16 ======
__global__ __launch_bounds__(256) void k_merge(
    const float* __restrict__ pp, const float* __restrict__ rot,
    const float* __restrict__ trans, ushort_t* __restrict__ feat16) {
  __shared__ float a0s[16], a1s[16];
  __shared__ float optg[288];
  int i = blockIdx.x, tid = threadIdx.x;
  const float* p0 = pp + ((size_t)i * 2 + 0) * 2048;
  const float* p1 = pp + ((size_t)i * 2 + 1) * 2048;
  ushort_t* Fi = feat16 + (size_t)i * FIN;

  if (tid < 16) {
    float m0 = p0[2016 + tid], m1 = p1[2016 + tid];
    float M = fmaxf(m0, m1);
    float s0 = __expf(m0 - M), s1 = __expf(m1 - M);
    float L = p0[2032 + tid] * s0 + p1[2032 + tid] * s1;
    float inv = (tid < Hh) ? 1.f / L : 0.f;
    a0s[tid] = s0 * inv;
    a1s[tid] = s1 * inv;
  }
  __syncthreads();

  for (int idx = tid; idx < 1728; idx += 256) {
    int h = (idx < 1536) ? (idx >> 7) : ((idx - 1536) >> 4);
    Fi[idx] = f2bf(p0[idx] * a0s[h] + p1[idx] * a1s[h]);
  }
  for (int idx = tid; idx < 288; idx += 256) {
    int h = idx / 24;
    optg[idx] = p0[1728 + idx] * a0s[h] + p1[1728 + idx] * a1s[h];
  }
  __syncthreads();

  if (tid < 96) {
    int h = tid >> 3, p = tid & 7;
    int cp = h * 24 + p * 3;
    float g0 = optg[cp + 0] - trans[i * 3 + 0];
    float g1 = optg[cp + 1] - trans[i * 3 + 1];
    float g2 = optg[cp + 2] - trans[i * 3 + 2];
    const float* R = rot + i * 9;
    float ss = 0.f;
#pragma unroll
    for (int nn2 = 0; nn2 < 3; ++nn2) {
      float o = R[nn2] * g0 + R[3 + nn2] * g1 + R[6 + nn2] * g2;   // R^T (g - t)
      Fi[1728 + cp + nn2] = f2bf(o);
      ss += o * o;
    }
    Fi[2016 + h * 8 + p] = f2bf(sqrtf(ss + 1e-12f));
  }
}

// ============ K5: out = feat16 @ WfT^T + bf (MFMA) ==========================
__global__ __launch_bounds__(64) void k_outm(
    const ushort_t* __restrict__ feat16, const ushort_t* __restrict__ WfT,
    const float* __restrict__ bfv, float* __restrict__ out) {
  int ot = blockIdx.x;                             // 0..23
  int i0 = blockIdx.y * 16;
  int l = threadIdx.x;
  int cl = l & 15, lk = l >> 4;
  f32x4 acc = {0.f, 0.f, 0.f, 0.f};
  const ushort_t* arow = feat16 + (size_t)(i0 + cl) * FIN;
  const ushort_t* brow = WfT + (size_t)(ot * 16 + cl) * FIN;
#pragma unroll 6
  for (int kk = 0; kk < 66; ++kk) {
    bf16x8 a = *(const bf16x8*)(arow + kk * 32 + lk * 8);
    bf16x8 b = *(const bf16x8*)(brow + kk * 32 + lk * 8);
    acc = __builtin_amdgcn_mfma_f32_16x16x32_bf16(a, b, acc, 0, 0, 0);
  }
  float bias = bfv[ot * 16 + cl];
#pragma unroll
  for (int r = 0; r < 4; ++r)
    out[(size_t)(i0 + lk * 4 + r) * CS + ot * 16 + cl] = acc[r] + bias;
}

// ============================ launcher ======================================
extern "C" void kernel_launch(void* const* d_in, const int* in_sizes, int n_in,
                              void* d_out, int out_size, void* d_ws, size_t ws_size,
                              hipStream_t stream) {
  const float* s_i   = (const float*)d_in[0];
  const float* z_ij  = (const float*)d_in[1];
  const float* rot   = (const float*)d_in[2];
  const float* trans = (const float*)d_in[3];
  const float* Wq    = (const float*)d_in[4];
  const float* Wk    = (const float*)d_in[5];
  const float* Wv    = (const float*)d_in[6];
  const float* Wqp   = (const float*)d_in[7];
  const float* Wkp   = (const float*)d_in[8];
  const float* Wvp   = (const float*)d_in[9];
  const float* Wb    = (const float*)d_in[10];
  const float* gamma = (const float*)d_in[11];
  const float* Wf    = (const float*)d_in[12];
  const float* bf    = (const float*)d_in[13];
  float* out = (float*)d_out;

  float* w = (float*)d_ws;
  float*    P     = w + OFF_P;
  float*    mq    = w + OFF_MQ;
  float*    mk    = w + OFF_MK;
  ushort_t* vT    = (ushort_t*)(w + OFF_VT);
  ushort_t* vpT   = (ushort_t*)(w + OFF_VPT);
  ushort_t* s16   = (ushort_t*)(w + OFF_S16);
  ushort_t* WcT   = (ushort_t*)(w + OFF_WCT);
  ushort_t* WfT   = (ushort_t*)(w + OFF_WFT);
  ushort_t* f16   = (ushort_t*)(w + OFF_F16);
  float*    pp    = w + OFF_PP;
  uint_t*   ekd   = (uint_t*)(w + OFF_EKD);
  ushort_t* vfrag = (ushort_t*)(w + OFF_VFRAG);
  ushort_t* eqb   = (ushort_t*)(w + OFF_EQB);
  ushort_t* wbf   = (ushort_t*)(w + OFF_WBF);

  k_s16<<<768, 256, 0, stream>>>(s_i, s16);
  k_wcatT<<<1152, 384, 0, stream>>>(Wq, Wk, Wv, Wqp, Wkp, Wvp, WcT);
  k_wfT<<<384, 256, 0, stream>>>(Wf, WfT);
  k_projm<<<dim3(72, 32), 64, 0, stream>>>(s16, WcT, P);
  k_prep<<<96, 64, 0, stream>>>(P, rot, trans, gamma, eqb, ekd, mq, mk, vT, vpT);
  k_wbfrag<<<1, 256, 0, stream>>>(Wb, wbf);
  k_vfrag<<<dim3(30, 16), 64, 0, stream>>>(vT, vpT, vfrag);
  k_fused6<<<dim3(512, 2), 512, 0, stream>>>(z_ij, eqb, ekd, wbf, mk, vfrag, pp);
  k_merge<<<512, 256, 0, stream>>>(pp, rot, trans, f16);
  k_outm<<<dim3(24, 32), 64, 0, stream>>>(f16, WfT, bf, out);
}